// Round 11
// baseline (527.844 us; speedup 1.0000x reference)
//
#include <hip/hip_runtime.h>

// LapCluster MI355X — round 11: r10 + atomic-free pooling + latency hiding.
// r10 post-mortem: 416us, kmid 94us steady (4x its ~25us floor), MfmaUtil 11%.
// Remaining excess traffic = global atomicMax pool flush (1.05M RMWs/dispatch
// ~= 64MB fetch + 64MB write at TCC — matches kmid's 135/124 vs 64/64 true).
// Remaining stall = global latency serialized in the 6-barrier tile chain
// (stage-in, in-loop arena frag loads, poolc gathers; only 2 blocks/CU).
// Fixes: (1) per-block PLAIN partial stores + 64-way max in pool_reduce
// (r6 scheme) — zero global atomics in stage kernels. (2) cross-tile register
// prefetch of stage-in + cluster ids. (3) loop-invariant weight fragments
// (w3/O2/F256) hoisted into VGPRs; w1/w2 frag loads early-issued per tile.
// __launch_bounds__(512,4) pins VGPR<=128 to keep 2 blocks/CU.
// Math unchanged: 16x16x32 bf16 MFMA, 3-term split (AhBh+AhBl+AlBh).
// A[m=lane&15][k=quad*8+j], B[k=quad*8+j][n=lane&15], D[m=quad*4+r][n=lane&15].
// Pool trick: W*[f3,pool] = W[:,:128]*f3 + poolc[o][cluster]; clusters in
// [0,16); ReLU>=0 -> float-bit max exact.

typedef __attribute__((ext_vector_type(8))) short bf16x8;
typedef __attribute__((ext_vector_type(4))) float f32x4;
typedef __attribute__((ext_vector_type(4))) unsigned u32x4;
typedef __attribute__((ext_vector_type(4))) float f32x4v;

#define MFMA16(a, b, c) __builtin_amdgcn_mfma_f32_16x16x32_bf16((a), (b), (c), 0, 0, 0)

#define TPB 512
#define PT 64
#define NPTS 131072
#define NC 16
#define TILES 4
#define NBLK 512         // 64 blocks/batch

#define FSB 136          // 128-ch plane stride (bf16 units)
#define ASB 72           // 64-ch plane stride
#define XSB 40           // 32-ch (padded x) plane stride

// frag arena units (1 unit = 64 lanes * 8 dwords: [0..3]=hi frag, [4..7]=lo)
#define U_F256 0
#define U_W1_0 16
#define U_W2_0 48
#define U_W3_0 64
#define U_W1_1 96
#define U_W2_1 112
#define U_W3_1 128
#define U_W1_2 160
#define U_W2_2 176
#define U_W3_2 192
#define U_O1   224
#define U_O2   256
#define N_UNITS 288

__device__ __forceinline__ f32x4 relu4(f32x4 a) {
#pragma unroll
  for (int r = 0; r < 4; ++r) a[r] = fmaxf(a[r], 0.f);
  return a;
}

__device__ __forceinline__ bf16x8 afrag(const short* plane, int stride, int mt, int ks) {
  const int lane = threadIdx.x & 63;
  return *reinterpret_cast<const bf16x8*>(
      plane + (mt * 16 + (lane & 15)) * stride + ks * 32 + (lane >> 4) * 8);
}

__device__ __forceinline__ void bfrag(const unsigned* __restrict__ arena, int unit,
                                      bf16x8& h, bf16x8& l) {
  const bf16x8* p = reinterpret_cast<const bf16x8*>(
      arena + ((size_t)unit * 64 + (threadIdx.x & 63)) * 8);
  h = p[0];
  l = p[1];
}

// write already-relu'd D (4 regs = pts mt*16 + quad*4 + r) as hi/lo bf16
__device__ __forceinline__ void store_planes(short* hp, short* lp, int stride,
                                             int mt, int n, f32x4 d) {
  const int m0 = mt * 16 + ((threadIdx.x & 63) >> 4) * 4;
#pragma unroll
  for (int r = 0; r < 4; ++r) {
    unsigned uv = __float_as_uint(d[r]);
    unsigned hm = uv & 0xFFFF0000u;
    float lo = d[r] - __uint_as_float(hm);
    hp[(m0 + r) * stride + n] = (short)(hm >> 16);
    lp[(m0 + r) * stride + n] = (short)(__float_as_uint(lo) >> 16);
  }
}

// unpack a prefetched packed-f3 u32x4 into hi/lo LDS planes
__device__ __forceinline__ void unpack_to_planes(u32x4 p, int idx, short* Fhi, short* Flo) {
  const int pt = idx >> 5, c4 = (idx & 31) * 4;
  uint2 hd, ld;
  hd.x = (p.y & 0xFFFF0000u) | (p.x >> 16);
  hd.y = (p.w & 0xFFFF0000u) | (p.z >> 16);
  ld.x = (p.y << 16) | (p.x & 0xFFFFu);
  ld.y = (p.w << 16) | (p.z & 0xFFFFu);
  *reinterpret_cast<uint2*>(&Fhi[pt * FSB + c4]) = hd;
  *reinterpret_cast<uint2*>(&Flo[pt * FSB + c4]) = ld;
}

// coalesced pack-write: hi/lo planes -> packed f3 global
__device__ __forceinline__ void write_f3(unsigned* __restrict__ f3g, int tile0,
                                         const short* Fhi, const short* Flo, int tid) {
  u32x4* dst = reinterpret_cast<u32x4*>(f3g + (size_t)tile0 * 128);
#pragma unroll
  for (int rr = 0; rr < 4; ++rr) {
    const int idx = rr * TPB + tid;
    const int pt = idx >> 5, c4 = (idx & 31) * 4;
    const uint2 hd = *reinterpret_cast<const uint2*>(&Fhi[pt * FSB + c4]);
    const uint2 ld = *reinterpret_cast<const uint2*>(&Flo[pt * FSB + c4]);
    u32x4 p;
    p.x = (hd.x << 16) | (ld.x & 0xFFFFu);
    p.y = (hd.x & 0xFFFF0000u) | (ld.x >> 16);
    p.z = (hd.y << 16) | (ld.y & 0xFFFFu);
    p.w = (hd.y & 0xFFFF0000u) | (ld.y >> 16);
    __builtin_nontemporal_store(p, dst + idx);
  }
}

// ---- prep: split weights into fragment-ordered hi/lo bf16 arenas
__global__ void __launch_bounds__(64) prep_frags(
    const float* __restrict__ w_in, const float* __restrict__ w1,
    const float* __restrict__ w2, const float* __restrict__ w3,
    const float* __restrict__ wo1, const float* __restrict__ wo2,
    unsigned* __restrict__ arena) {
  const int unit = blockIdx.x;
  const int lane = threadIdx.x;
  const float* W; int KS, Klog, rs, u;
  if (unit < U_W1_0)      { W = w_in;                   u = unit - U_F256; KS = 1; Klog = 28;  rs = 28;  }
  else if (unit < U_W2_0) { W = w1;                     u = unit - U_W1_0; KS = 8; Klog = 256; rs = 256; }
  else if (unit < U_W3_0) { W = w2;                     u = unit - U_W2_0; KS = 2; Klog = 64;  rs = 64;  }
  else if (unit < U_W1_1) { W = w3;                     u = unit - U_W3_0; KS = 4; Klog = 128; rs = 128; }
  else if (unit < U_W2_1) { W = w1 + 64 * 256;          u = unit - U_W1_1; KS = 4; Klog = 128; rs = 256; }
  else if (unit < U_W3_1) { W = w2 + 128 * 64;          u = unit - U_W2_1; KS = 2; Klog = 64;  rs = 64;  }
  else if (unit < U_W1_2) { W = w3 + 128 * 128;         u = unit - U_W3_1; KS = 4; Klog = 128; rs = 128; }
  else if (unit < U_W2_2) { W = w1 + 2 * 64 * 256;      u = unit - U_W1_2; KS = 4; Klog = 128; rs = 256; }
  else if (unit < U_W3_2) { W = w2 + 2 * 128 * 64;      u = unit - U_W2_2; KS = 2; Klog = 64;  rs = 64;  }
  else if (unit < U_O1)   { W = w3 + 2 * 128 * 128;     u = unit - U_W3_2; KS = 4; Klog = 128; rs = 128; }
  else if (unit < U_O2)   { W = wo1;                    u = unit - U_O1;   KS = 4; Klog = 128; rs = 256; }
  else                    { W = wo2;                    u = unit - U_O2;   KS = 4; Klog = 128; rs = 128; }
  const int nt = u / KS, ks = u % KS;
  const int n = nt * 16 + (lane & 15);
  const int k0 = ks * 32 + (lane >> 4) * 8;
  unsigned hiD[4], loD[4];
#pragma unroll
  for (int d = 0; d < 4; ++d) {
    unsigned hu[2], lu[2];
#pragma unroll
    for (int e = 0; e < 2; ++e) {
      const int k = k0 + d * 2 + e;
      float v = (k < Klog) ? W[(size_t)n * rs + k] : 0.f;
      unsigned uv = __float_as_uint(v);
      unsigned hm = uv & 0xFFFF0000u;
      float lo = v - __uint_as_float(hm);
      hu[e] = hm >> 16;
      lu[e] = __float_as_uint(lo) >> 16;
    }
    hiD[d] = hu[0] | (hu[1] << 16);
    loD[d] = lu[0] | (lu[1] << 16);
  }
  unsigned* dst = arena + ((size_t)unit * 64 + lane) * 8;
  *reinterpret_cast<uint4*>(dst)     = make_uint4(hiD[0], hiD[1], hiD[2], hiD[3]);
  *reinterpret_cast<uint4*>(dst + 4) = make_uint4(loD[0], loD[1], loD[2], loD[3]);
}

// ---- per-batch poolc table: 64-way max over block partials, then W[:,128:]*pool
template<int O>
__global__ void __launch_bounds__(1024) pool_reduce_kern(
    const unsigned* __restrict__ part, const float* __restrict__ W,
    const float* __restrict__ bias, float* __restrict__ poolc_g) {
  __shared__ float pfL[2048];        // [ch][cl] = ch*16+cl
  __shared__ float Wl[O * 129];
  const int tid = threadIdx.x;
  const int b = blockIdx.x;
  for (int i = tid; i < 2048; i += 1024) {
    float m = 0.f;
    const unsigned* pp = part + (size_t)(b * 64) * 2048 + i;
    for (int blk = 0; blk < 64; ++blk) m = fmaxf(m, __uint_as_float(pp[(size_t)blk * 2048]));
    pfL[i] = m;
  }
  for (int i = tid; i < O * 128; i += 1024) {
    const int o = i >> 7, k = i & 127;
    Wl[o * 129 + k] = W[o * 256 + 128 + k];
  }
  __syncthreads();
  constexpr int SH = (O == 64) ? 6 : 7;
  for (int e = tid; e < O * 16; e += 1024) {
    const int o = e & (O - 1);
    const int cl = e >> SH;
    float s = bias[o];
    const float* wr = &Wl[o * 129];
    const float* pr = &pfL[cl];
#pragma unroll 4
    for (int k = 0; k < 128; ++k) s = fmaf(wr[k], pr[k * 16], s);
    poolc_g[(size_t)b * (O * 16) + o * 16 + cl] = s;
  }
}

// ---- Stage 0: x -> f256 -> f64(w1[0]) -> f128(w2[0], pooled) -> f3_0(w3[0])
__global__ void __launch_bounds__(TPB, 4) k0_kern(
    const float* __restrict__ x, const int* __restrict__ cls,
    const float* __restrict__ b_in, const float* __restrict__ b1,
    const float* __restrict__ b2, const float* __restrict__ b3,
    const unsigned* __restrict__ arena,
    unsigned* __restrict__ f3g, unsigned* __restrict__ part0) {
  __shared__ short Fhi[PT * FSB], Flo[PT * FSB];
  __shared__ short XA[PT * ASB * 2];               // x planes alias A64 planes
  __shared__ unsigned pool_s[128 * NC];
  short* Xhi = XA;  short* Xlo = XA + PT * XSB;
  short* Ahi = XA;  short* Alo = XA + PT * ASB;
  const int tid = threadIdx.x;
  const int lane = tid & 63, w = tid >> 6, l15 = lane & 15, quad = lane >> 4;
  const int Nt1 = w & 3, mh = w >> 2;
  for (int i = tid; i < 128 * NC; i += TPB) pool_s[i] = 0u;

  float biH[2];
#pragma unroll
  for (int c = 0; c < 2; ++c) biH[c] = b_in[c * 128 + w * 16 + l15];
  const float b1H = b1[Nt1 * 16 + l15];
  const float b2H = b2[w * 16 + l15];
  const float b3H = b3[w * 16 + l15];
  const int n1 = Nt1 * 16 + l15;
  const int n2 = w * 16 + l15;
  const int xpt = (tid < 448) ? tid / 7 : 0;
  const int xc4 = (tid < 448) ? (tid - xpt * 7) * 4 : 0;

  // hoisted loop-invariant frags: F256 (2 units) + W3 (4 units)
  bf16x8 fch[2], fcl[2], w3h[4], w3l[4];
#pragma unroll
  for (int c = 0; c < 2; ++c) bfrag(arena, U_F256 + c * 8 + w, fch[c], fcl[c]);
#pragma unroll
  for (int ks = 0; ks < 4; ++ks) bfrag(arena, U_W3_0 + w * 4 + ks, w3h[ks], w3l[ks]);

  const int tb0 = blockIdx.x * TILES * PT;
  f32x4v xpre = {};
  if (tid < 448)
    xpre = __builtin_nontemporal_load(
        reinterpret_cast<const f32x4v*>(x + (size_t)(tb0 + xpt) * 28 + xc4));

  for (int t = 0; t < TILES; ++t) {
    const int tile0 = tb0 + t * PT;
    if (tid < 448) {   // stage prefetched x hi/lo
      const f32x4v v = xpre;
      unsigned h0 = __float_as_uint(v.x) & 0xFFFF0000u, h1 = __float_as_uint(v.y) & 0xFFFF0000u;
      unsigned h2 = __float_as_uint(v.z) & 0xFFFF0000u, h3 = __float_as_uint(v.w) & 0xFFFF0000u;
      uint2 hd, ld;
      hd.x = (h0 >> 16) | h1;
      hd.y = (h2 >> 16) | h3;
      ld.x = (__float_as_uint(v.x - __uint_as_float(h0)) >> 16) |
             (__float_as_uint(v.y - __uint_as_float(h1)) & 0xFFFF0000u);
      ld.y = (__float_as_uint(v.z - __uint_as_float(h2)) >> 16) |
             (__float_as_uint(v.w - __uint_as_float(h3)) & 0xFFFF0000u);
      *reinterpret_cast<uint2*>(&Xhi[xpt * XSB + xc4]) = hd;
      *reinterpret_cast<uint2*>(&Xlo[xpt * XSB + xc4]) = ld;
    } else {           // zero k pads 28..31 (region aliased by A64 last tile)
      const int p = tid - 448;
      *reinterpret_cast<uint2*>(&Xhi[p * XSB + 28]) = make_uint2(0u, 0u);
      *reinterpret_cast<uint2*>(&Xlo[p * XSB + 28]) = make_uint2(0u, 0u);
    }
    int clP[4][4];
#pragma unroll
    for (int Mt = 0; Mt < 4; ++Mt) {
      int4 v = *reinterpret_cast<const int4*>(cls + tile0 + Mt * 16 + quad * 4);
      clP[Mt][0] = v.x; clP[Mt][1] = v.y; clP[Mt][2] = v.z; clP[Mt][3] = v.w;
    }
    // early-issue in-loop frags: W2 (2 units)
    bf16x8 w2h[2], w2l[2];
#pragma unroll
    for (int ks = 0; ks < 2; ++ks) bfrag(arena, U_W2_0 + w * 2 + ks, w2h[ks], w2l[ks]);
    __syncthreads();   // B1
    if (t + 1 < TILES && tid < 448)
      xpre = __builtin_nontemporal_load(
          reinterpret_cast<const f32x4v*>(x + (size_t)(tile0 + PT + xpt) * 28 + xc4));
    f32x4 a1[2];
#pragma unroll
    for (int m = 0; m < 2; ++m) a1[m] = {b1H, b1H, b1H, b1H};
#pragma unroll 1
    for (int c = 0; c < 2; ++c) {
      // early-issue w1 frags for this chunk (4 units)
      bf16x8 w1h[4], w1l[4];
#pragma unroll
      for (int ks = 0; ks < 4; ++ks)
        bfrag(arena, U_W1_0 + Nt1 * 8 + c * 4 + ks, w1h[ks], w1l[ks]);
      // f256 chunk c: wave owns 16 channels, all 4 Mt
      f32x4 f6[4];
#pragma unroll
      for (int Mt = 0; Mt < 4; ++Mt) {
        f6[Mt] = {biH[c], biH[c], biH[c], biH[c]};
        const bf16x8 xah = afrag(Xhi, XSB, Mt, 0), xal = afrag(Xlo, XSB, Mt, 0);
        f6[Mt] = MFMA16(xal, fch[c], MFMA16(xah, fcl[c], MFMA16(xah, fch[c], f6[Mt])));
      }
#pragma unroll
      for (int Mt = 0; Mt < 4; ++Mt)
        store_planes(Fhi, Flo, FSB, Mt, n2, relu4(f6[Mt]));
      __syncthreads();   // B2 / B4: chunk staged, X reads done
#pragma unroll
      for (int ks = 0; ks < 4; ++ks) {
#pragma unroll
        for (int m = 0; m < 2; ++m) {
          const bf16x8 ah = afrag(Fhi, FSB, mh * 2 + m, ks), al = afrag(Flo, FSB, mh * 2 + m, ks);
          a1[m] = MFMA16(al, w1h[ks], MFMA16(ah, w1l[ks], MFMA16(ah, w1h[ks], a1[m])));
        }
      }
      if (c == 1) {      // A64 write into XA: all X reads done (post-B4)
#pragma unroll
        for (int m = 0; m < 2; ++m)
          store_planes(Ahi, Alo, ASB, mh * 2 + m, n1, relu4(a1[m]));
      }
      __syncthreads();   // B3 / B5: chunk F-reads done (c=1: A staged)
    }
    // w2: wave owns 16 of 128 out, K=64, all Mt
    f32x4 f2[4];
#pragma unroll
    for (int Mt = 0; Mt < 4; ++Mt) f2[Mt] = {b2H, b2H, b2H, b2H};
#pragma unroll
    for (int ks = 0; ks < 2; ++ks) {
#pragma unroll
      for (int Mt = 0; Mt < 4; ++Mt) {
        const bf16x8 ah = afrag(Ahi, ASB, Mt, ks), al = afrag(Alo, ASB, Mt, ks);
        f2[Mt] = MFMA16(al, w2h[ks], MFMA16(ah, w2l[ks], MFMA16(ah, w2h[ks], f2[Mt])));
      }
    }
#pragma unroll
    for (int Mt = 0; Mt < 4; ++Mt) {
      f32x4 d = relu4(f2[Mt]);
#pragma unroll
      for (int r = 0; r < 4; ++r)
        atomicMax(&pool_s[n2 * NC + clP[Mt][r]], __float_as_uint(d[r]));
      store_planes(Fhi, Flo, FSB, Mt, n2, d);   // F w1-readers done at B5
    }
    __syncthreads();   // B6: f128 staged
    // w3 (hoisted frags): wave owns 16 of 128 out, K=128, all Mt
    f32x4 f3a[4];
#pragma unroll
    for (int Mt = 0; Mt < 4; ++Mt) f3a[Mt] = {b3H, b3H, b3H, b3H};
#pragma unroll
    for (int ks = 0; ks < 4; ++ks) {
#pragma unroll
      for (int Mt = 0; Mt < 4; ++Mt) {
        const bf16x8 ah = afrag(Fhi, FSB, Mt, ks), al = afrag(Flo, FSB, Mt, ks);
        f3a[Mt] = MFMA16(al, w3h[ks], MFMA16(ah, w3l[ks], MFMA16(ah, w3h[ks], f3a[Mt])));
      }
    }
    __syncthreads();   // B7: all w3 F-reads done
#pragma unroll
    for (int Mt = 0; Mt < 4; ++Mt)
      store_planes(Fhi, Flo, FSB, Mt, n2, relu4(f3a[Mt]));
    __syncthreads();   // B8: f3 planes staged
    write_f3(f3g, tile0, Fhi, Flo, tid);
    // no end barrier: next x-stage writes XA (readers fenced by B6);
    // next F-writes post-next-B1 fence prior pack-reads per-thread order.
  }
  for (int i = tid; i < 128 * NC; i += TPB)
    part0[(size_t)blockIdx.x * 2048 + i] = pool_s[i];   // plain store (no atomics)
}

// ---- Stages 1,2: f3 -> f64(w1+poolc) -> f128(w2, pooled) -> f3'(w3)
__global__ void __launch_bounds__(TPB, 4) kmid_kern(
    unsigned* __restrict__ f3g, const unsigned* __restrict__ arena,
    const float* __restrict__ poolc_g, unsigned* __restrict__ part_cur,
    const int* __restrict__ clg, const int* __restrict__ clp,
    const float* __restrict__ b2s, const float* __restrict__ b3s,
    int uW1, int uW2, int uW3) {
  __shared__ short Fhi[PT * FSB], Flo[PT * FSB];
  __shared__ short Ahi[PT * ASB], Alo[PT * ASB];
  __shared__ unsigned pool_s[128 * NC];
  const int tid = threadIdx.x;
  const int lane = tid & 63, w = tid >> 6, l15 = lane & 15, quad = lane >> 4;
  const int b = blockIdx.x >> 6;
  const int Nt1 = w & 3, mh = w >> 2;
  for (int i = tid; i < 128 * NC; i += TPB) pool_s[i] = 0u;
  const float b2H = b2s[w * 16 + l15];
  const float b3H = b3s[w * 16 + l15];
  const int n1 = Nt1 * 16 + l15;
  const int n2 = w * 16 + l15;

  // hoisted loop-invariant w3 frags (4 units)
  bf16x8 w3h[4], w3l[4];
#pragma unroll
  for (int ks = 0; ks < 4; ++ks) bfrag(arena, uW3 + w * 4 + ks, w3h[ks], w3l[ks]);

  const int tb0 = blockIdx.x * TILES * PT;
  const u32x4* srcAll = reinterpret_cast<const u32x4*>(f3g);
  u32x4 p[4];
  int4 cg0, cg1;
#pragma unroll
  for (int rr = 0; rr < 4; ++rr)
    p[rr] = __builtin_nontemporal_load(srcAll + (size_t)tb0 * 32 + rr * TPB + tid);
  cg0 = *reinterpret_cast<const int4*>(clg + tb0 + (mh * 2 + 0) * 16 + quad * 4);
  cg1 = *reinterpret_cast<const int4*>(clg + tb0 + (mh * 2 + 1) * 16 + quad * 4);

  for (int t = 0; t < TILES; ++t) {
    const int tile0 = tb0 + t * PT;
#pragma unroll
    for (int rr = 0; rr < 4; ++rr) unpack_to_planes(p[rr], rr * TPB + tid, Fhi, Flo);
    int clP[4][4];
#pragma unroll
    for (int Mt = 0; Mt < 4; ++Mt) {
      int4 v = *reinterpret_cast<const int4*>(clp + tile0 + Mt * 16 + quad * 4);
      clP[Mt][0] = v.x; clP[Mt][1] = v.y; clP[Mt][2] = v.z; clP[Mt][3] = v.w;
    }
    const int4 cgA = cg0, cgB = cg1;
    // early-issue in-loop frags: w1 (4 units) + w2 (2 units)
    bf16x8 w1h[4], w1l[4], w2h[2], w2l[2];
#pragma unroll
    for (int ks = 0; ks < 4; ++ks) bfrag(arena, uW1 + Nt1 * 4 + ks, w1h[ks], w1l[ks]);
#pragma unroll
    for (int ks = 0; ks < 2; ++ks) bfrag(arena, uW2 + w * 2 + ks, w2h[ks], w2l[ks]);
    __syncthreads();   // B1: staged
    if (t + 1 < TILES) {
#pragma unroll
      for (int rr = 0; rr < 4; ++rr)
        p[rr] = __builtin_nontemporal_load(srcAll + (size_t)(tile0 + PT) * 32 + rr * TPB + tid);
      cg0 = *reinterpret_cast<const int4*>(clg + tile0 + PT + (mh * 2 + 0) * 16 + quad * 4);
      cg1 = *reinterpret_cast<const int4*>(clg + tile0 + PT + (mh * 2 + 1) * 16 + quad * 4);
    }
    // w1: wave owns 16 of 64 out (Nt1), K=128, Mt = mh*2+m
    f32x4 a1[2];
    {
      const float* pcb = poolc_g + (size_t)b * 1024 + n1 * 16;
      a1[0][0] = pcb[cgA.x]; a1[0][1] = pcb[cgA.y]; a1[0][2] = pcb[cgA.z]; a1[0][3] = pcb[cgA.w];
      a1[1][0] = pcb[cgB.x]; a1[1][1] = pcb[cgB.y]; a1[1][2] = pcb[cgB.z]; a1[1][3] = pcb[cgB.w];
    }
#pragma unroll
    for (int ks = 0; ks < 4; ++ks) {
#pragma unroll
      for (int m = 0; m < 2; ++m) {
        const bf16x8 ah = afrag(Fhi, FSB, mh * 2 + m, ks), al = afrag(Flo, FSB, mh * 2 + m, ks);
        a1[m] = MFMA16(al, w1h[ks], MFMA16(ah, w1l[ks], MFMA16(ah, w1h[ks], a1[m])));
      }
    }
#pragma unroll
    for (int m = 0; m < 2; ++m)
      store_planes(Ahi, Alo, ASB, mh * 2 + m, n1, relu4(a1[m]));
    __syncthreads();   // B2: A64 staged
    // w2: wave owns 16 of 128 out, K=64, all Mt
    f32x4 f2[4];
#pragma unroll
    for (int Mt = 0; Mt < 4; ++Mt) f2[Mt] = {b2H, b2H, b2H, b2H};
#pragma unroll
    for (int ks = 0; ks < 2; ++ks) {
#pragma unroll
      for (int Mt = 0; Mt < 4; ++Mt) {
        const bf16x8 ah = afrag(Ahi, ASB, Mt, ks), al = afrag(Alo, ASB, Mt, ks);
        f2[Mt] = MFMA16(al, w2h[ks], MFMA16(ah, w2l[ks], MFMA16(ah, w2h[ks], f2[Mt])));
      }
    }
#pragma unroll
    for (int Mt = 0; Mt < 4; ++Mt) {
      f32x4 d = relu4(f2[Mt]);
#pragma unroll
      for (int r = 0; r < 4; ++r)
        atomicMax(&pool_s[n2 * NC + clP[Mt][r]], __float_as_uint(d[r]));
      store_planes(Fhi, Flo, FSB, Mt, n2, d);   // F w1-readers done at B2
    }
    __syncthreads();   // B3: f128 staged
    // w3 (hoisted): wave owns 16 of 128 out, K=128, all Mt
    f32x4 f3a[4];
#pragma unroll
    for (int Mt = 0; Mt < 4; ++Mt) f3a[Mt] = {b3H, b3H, b3H, b3H};
#pragma unroll
    for (int ks = 0; ks < 4; ++ks) {
#pragma unroll
      for (int Mt = 0; Mt < 4; ++Mt) {
        const bf16x8 ah = afrag(Fhi, FSB, Mt, ks), al = afrag(Flo, FSB, Mt, ks);
        f3a[Mt] = MFMA16(al, w3h[ks], MFMA16(ah, w3l[ks], MFMA16(ah, w3h[ks], f3a[Mt])));
      }
    }
    __syncthreads();   // B4: all w3 F-reads done
#pragma unroll
    for (int Mt = 0; Mt < 4; ++Mt)
      store_planes(Fhi, Flo, FSB, Mt, n2, relu4(f3a[Mt]));
    __syncthreads();   // B5: f3 planes staged
    write_f3(f3g, tile0, Fhi, Flo, tid);
    __syncthreads();   // B6: pack-reads done before next stage-in overwrite
  }
  for (int i = tid; i < 128 * NC; i += TPB)
    part_cur[(size_t)blockIdx.x * 2048 + i] = pool_s[i];   // plain store
}

// ---- Head: f3_2 -> o1(wo1+poolco) -> o2(wo2) -> global max
__global__ void __launch_bounds__(TPB, 4) k3_kern(
    const unsigned* __restrict__ f3g, const unsigned* __restrict__ arena,
    const float* __restrict__ poolco_g, const int* __restrict__ clg,
    const float* __restrict__ bo2, unsigned* __restrict__ out) {
  __shared__ short Fhi[PT * FSB], Flo[PT * FSB];
  const int tid = threadIdx.x;
  const int lane = tid & 63, w = tid >> 6, l15 = lane & 15, quad = lane >> 4;
  const int b = blockIdx.x >> 6;
  const float bo2H = bo2[w * 16 + l15];
  const int n2 = w * 16 + l15;
  float omax = 0.f;

  // hoisted O2 frags (4 units)
  bf16x8 o2h[4], o2l[4];
#pragma unroll
  for (int ks = 0; ks < 4; ++ks) bfrag(arena, U_O2 + w * 4 + ks, o2h[ks], o2l[ks]);

  const int tb0 = blockIdx.x * TILES * PT;
  const u32x4* srcAll = reinterpret_cast<const u32x4*>(f3g);
  u32x4 p[4];
#pragma unroll
  for (int rr = 0; rr < 4; ++rr)
    p[rr] = __builtin_nontemporal_load(srcAll + (size_t)tb0 * 32 + rr * TPB + tid);

  for (int t = 0; t < TILES; ++t) {
    const int tile0 = tb0 + t * PT;
#pragma unroll
    for (int rr = 0; rr < 4; ++rr) unpack_to_planes(p[rr], rr * TPB + tid, Fhi, Flo);
    int clA[4][4];
#pragma unroll
    for (int Mt = 0; Mt < 4; ++Mt) {
      int4 v = *reinterpret_cast<const int4*>(clg + tile0 + Mt * 16 + quad * 4);
      clA[Mt][0] = v.x; clA[Mt][1] = v.y; clA[Mt][2] = v.z; clA[Mt][3] = v.w;
    }
    // early-issue O1 frags (4 units)
    bf16x8 o1h[4], o1l[4];
#pragma unroll
    for (int ks = 0; ks < 4; ++ks) bfrag(arena, U_O1 + w * 4 + ks, o1h[ks], o1l[ks]);
    __syncthreads();   // B1
    if (t + 1 < TILES) {
#pragma unroll
      for (int rr = 0; rr < 4; ++rr)
        p[rr] = __builtin_nontemporal_load(srcAll + (size_t)(tile0 + PT) * 32 + rr * TPB + tid);
    }
    f32x4 o1a[4];
#pragma unroll
    for (int Mt = 0; Mt < 4; ++Mt) {
      const float* pcb = poolco_g + (size_t)b * 2048 + n2 * 16;
      o1a[Mt][0] = pcb[clA[Mt][0]]; o1a[Mt][1] = pcb[clA[Mt][1]];
      o1a[Mt][2] = pcb[clA[Mt][2]]; o1a[Mt][3] = pcb[clA[Mt][3]];
    }
#pragma unroll
    for (int ks = 0; ks < 4; ++ks) {
#pragma unroll
      for (int Mt = 0; Mt < 4; ++Mt) {
        const bf16x8 ah = afrag(Fhi, FSB, Mt, ks), al = afrag(Flo, FSB, Mt, ks);
        o1a[Mt] = MFMA16(al, o1h[ks], MFMA16(ah, o1l[ks], MFMA16(ah, o1h[ks], o1a[Mt])));
      }
    }
    __syncthreads();   // B2: o1 F-reads done
#pragma unroll
    for (int Mt = 0; Mt < 4; ++Mt)
      store_planes(Fhi, Flo, FSB, Mt, n2, relu4(o1a[Mt]));
    __syncthreads();   // B3: o1 staged
    f32x4 o2a[4];
#pragma unroll
    for (int Mt = 0; Mt < 4; ++Mt) o2a[Mt] = {bo2H, bo2H, bo2H, bo2H};
#pragma unroll
    for (int ks = 0; ks < 4; ++ks) {
#pragma unroll
      for (int Mt = 0; Mt < 4; ++Mt) {
        const bf16x8 ah = afrag(Fhi, FSB, Mt, ks), al = afrag(Flo, FSB, Mt, ks);
        o2a[Mt] = MFMA16(al, o2h[ks], MFMA16(ah, o2l[ks], MFMA16(ah, o2h[ks], o2a[Mt])));
      }
    }
#pragma unroll
    for (int Mt = 0; Mt < 4; ++Mt) {
      f32x4 d = relu4(o2a[Mt]);
      omax = fmaxf(omax, fmaxf(fmaxf(d[0], d[1]), fmaxf(d[2], d[3])));
    }
    __syncthreads();   // B4: o2 F-reads done before next stage-in
  }
  omax = fmaxf(omax, __shfl_xor(omax, 16));
  omax = fmaxf(omax, __shfl_xor(omax, 32));
  if (lane < 16)
    atomicMax(&out[b * 128 + w * 16 + lane], __float_as_uint(omax));
}

extern "C" void kernel_launch(void* const* d_in, const int* in_sizes, int n_in,
                              void* d_out, int out_size, void* d_ws, size_t ws_size,
                              hipStream_t stream) {
  const float* x    = (const float*)d_in[0];
  const int*   cls  = (const int*)d_in[1];
  const float* w_in = (const float*)d_in[2];
  const float* b_in = (const float*)d_in[3];
  const float* w1   = (const float*)d_in[4];
  const float* b1   = (const float*)d_in[5];
  const float* w2   = (const float*)d_in[6];
  const float* b2   = (const float*)d_in[7];
  const float* w3   = (const float*)d_in[8];
  const float* b3   = (const float*)d_in[9];
  const float* wo1  = (const float*)d_in[10];
  const float* bo1  = (const float*)d_in[11];
  const float* wo2  = (const float*)d_in[12];
  const float* bo2  = (const float*)d_in[13];

  char* ws = (char*)d_ws;
  unsigned* f3g = (unsigned*)ws;                            // 64 MB packed hi|lo
  unsigned* part0 = (unsigned*)(ws + ((size_t)64 << 20));   // 3 x 4 MB (per-block)
  unsigned* part1 = part0 + (size_t)NBLK * 2048;
  unsigned* part2 = part1 + (size_t)NBLK * 2048;
  float* poolc1 = (float*)(part2 + (size_t)NBLK * 2048);    // 8*1024
  float* poolc2 = poolc1 + 8 * 1024;
  float* poolco = poolc2 + 8 * 1024;                        // 8*2048
  unsigned* arena = (unsigned*)(poolco + 8 * 2048);         // 288*512 dwords

  hipMemsetAsync(d_out, 0, 1024 * sizeof(float), stream);

  prep_frags<<<N_UNITS, 64, 0, stream>>>(w_in, w1, w2, w3, wo1, wo2, arena);
  k0_kern<<<NBLK, TPB, 0, stream>>>(x, cls, b_in, b1, b2, b3, arena, f3g, part0);
  pool_reduce_kern<64><<<8, 1024, 0, stream>>>(part0, w1 + (size_t)64 * 256, b1 + 64, poolc1);
  kmid_kern<<<NBLK, TPB, 0, stream>>>(f3g, arena, poolc1, part1, cls, cls + NPTS,
                                      b2 + 128, b3 + 128, U_W1_1, U_W2_1, U_W3_1);
  pool_reduce_kern<64><<<8, 1024, 0, stream>>>(part1, w1 + (size_t)2 * 64 * 256, b1 + 128, poolc2);
  kmid_kern<<<NBLK, TPB, 0, stream>>>(f3g, arena, poolc2, part2, cls + NPTS, cls + 2 * NPTS,
                                      b2 + 256, b3 + 256, U_W1_2, U_W2_2, U_W3_2);
  pool_reduce_kern<128><<<8, 1024, 0, stream>>>(part2, wo1, bo1, poolco);
  k3_kern<<<NBLK, TPB, 0, stream>>>(f3g, arena, poolco, cls + 2 * NPTS, bo2, (unsigned*)d_out);
}

// Round 12
// 477.319 us; speedup vs baseline: 1.1059x; 1.1059x over previous
//
#include <hip/hip_runtime.h>

// LapCluster MI355X — round 12: r10 + atomic-free pooling ONLY.
// r11 post-mortem: hoisting 18 weight-frag units into VGPRs exceeded the
// allocator's 64-VGPR choice -> scratch spills (k0 FETCH 64->186MB, WRITE
// 107->173MB) -> 416->528us regression. Lesson: bfrag-at-use was fine (L2
// resident); register strategy must respect the budget.
// r12 = r10 verbatim except: pool partials flushed with PLAIN per-block
// stores (part[block][2048]) and pool_reduce does a 64-way max — removes
// 1.05M global atomicMax RMWs (~64MB fetch + ~60MB write) per stage kernel.
// Math: 16x16x32 bf16 MFMA, 3-term split (AhBh+AhBl+AlBh).
// A[m=lane&15][k=quad*8+j], B[k=quad*8+j][n=lane&15], D[m=quad*4+r][n=lane&15].
// Pool trick: W*[f3,pool] = W[:,:128]*f3 + poolc[o][cluster]; clusters in
// [0,16); ReLU>=0 -> float-bit max exact.

typedef __attribute__((ext_vector_type(8))) short bf16x8;
typedef __attribute__((ext_vector_type(4))) float f32x4;
typedef __attribute__((ext_vector_type(4))) unsigned u32x4;
typedef __attribute__((ext_vector_type(4))) float f32x4v;

#define MFMA16(a, b, c) __builtin_amdgcn_mfma_f32_16x16x32_bf16((a), (b), (c), 0, 0, 0)

#define TPB 512
#define PT 64
#define NPTS 131072
#define NC 16
#define TILES 4
#define NBLK 512         // 64 blocks/batch

#define FSB 136          // 128-ch plane stride (bf16 units)
#define ASB 72           // 64-ch plane stride
#define XSB 40           // 32-ch (padded x) plane stride

// frag arena units (1 unit = 64 lanes * 8 dwords: [0..3]=hi frag, [4..7]=lo)
#define U_F256 0
#define U_W1_0 16
#define U_W2_0 48
#define U_W3_0 64
#define U_W1_1 96
#define U_W2_1 112
#define U_W3_1 128
#define U_W1_2 160
#define U_W2_2 176
#define U_W3_2 192
#define U_O1   224
#define U_O2   256
#define N_UNITS 288

__device__ __forceinline__ f32x4 relu4(f32x4 a) {
#pragma unroll
  for (int r = 0; r < 4; ++r) a[r] = fmaxf(a[r], 0.f);
  return a;
}

__device__ __forceinline__ bf16x8 afrag(const short* plane, int stride, int mt, int ks) {
  const int lane = threadIdx.x & 63;
  return *reinterpret_cast<const bf16x8*>(
      plane + (mt * 16 + (lane & 15)) * stride + ks * 32 + (lane >> 4) * 8);
}

__device__ __forceinline__ void bfrag(const unsigned* __restrict__ arena, int unit,
                                      bf16x8& h, bf16x8& l) {
  const bf16x8* p = reinterpret_cast<const bf16x8*>(
      arena + ((size_t)unit * 64 + (threadIdx.x & 63)) * 8);
  h = p[0];
  l = p[1];
}

// write already-relu'd D (4 regs = pts mt*16 + quad*4 + r) as hi/lo bf16
__device__ __forceinline__ void store_planes(short* hp, short* lp, int stride,
                                             int mt, int n, f32x4 d) {
  const int m0 = mt * 16 + ((threadIdx.x & 63) >> 4) * 4;
#pragma unroll
  for (int r = 0; r < 4; ++r) {
    unsigned uv = __float_as_uint(d[r]);
    unsigned hm = uv & 0xFFFF0000u;
    float lo = d[r] - __uint_as_float(hm);
    hp[(m0 + r) * stride + n] = (short)(hm >> 16);
    lp[(m0 + r) * stride + n] = (short)(__float_as_uint(lo) >> 16);
  }
}

// coalesced stage-in: packed f3 (hi<<16|lo) -> hi/lo LDS planes
__device__ __forceinline__ void stage_f3(const unsigned* __restrict__ f3g, int tile0,
                                         short* Fhi, short* Flo, int tid) {
  const u32x4* src = reinterpret_cast<const u32x4*>(f3g + (size_t)tile0 * 128);
#pragma unroll
  for (int rr = 0; rr < 4; ++rr) {
    const int idx = rr * TPB + tid;
    const u32x4 p = __builtin_nontemporal_load(src + idx);
    const int pt = idx >> 5, c4 = (idx & 31) * 4;
    uint2 hd, ld;
    hd.x = (p.y & 0xFFFF0000u) | (p.x >> 16);
    hd.y = (p.w & 0xFFFF0000u) | (p.z >> 16);
    ld.x = (p.y << 16) | (p.x & 0xFFFFu);
    ld.y = (p.w << 16) | (p.z & 0xFFFFu);
    *reinterpret_cast<uint2*>(&Fhi[pt * FSB + c4]) = hd;
    *reinterpret_cast<uint2*>(&Flo[pt * FSB + c4]) = ld;
  }
}

// coalesced pack-write: hi/lo planes -> packed f3 global (inverse of stage_f3)
__device__ __forceinline__ void write_f3(unsigned* __restrict__ f3g, int tile0,
                                         const short* Fhi, const short* Flo, int tid) {
  u32x4* dst = reinterpret_cast<u32x4*>(f3g + (size_t)tile0 * 128);
#pragma unroll
  for (int rr = 0; rr < 4; ++rr) {
    const int idx = rr * TPB + tid;
    const int pt = idx >> 5, c4 = (idx & 31) * 4;
    const uint2 hd = *reinterpret_cast<const uint2*>(&Fhi[pt * FSB + c4]);
    const uint2 ld = *reinterpret_cast<const uint2*>(&Flo[pt * FSB + c4]);
    u32x4 p;
    p.x = (hd.x << 16) | (ld.x & 0xFFFFu);
    p.y = (hd.x & 0xFFFF0000u) | (ld.x >> 16);
    p.z = (hd.y << 16) | (ld.y & 0xFFFFu);
    p.w = (hd.y & 0xFFFF0000u) | (ld.y >> 16);
    __builtin_nontemporal_store(p, dst + idx);
  }
}

// ---- prep: split weights into fragment-ordered hi/lo bf16 arenas
__global__ void __launch_bounds__(64) prep_frags(
    const float* __restrict__ w_in, const float* __restrict__ w1,
    const float* __restrict__ w2, const float* __restrict__ w3,
    const float* __restrict__ wo1, const float* __restrict__ wo2,
    unsigned* __restrict__ arena) {
  const int unit = blockIdx.x;
  const int lane = threadIdx.x;
  const float* W; int KS, Klog, rs, u;
  if (unit < U_W1_0)      { W = w_in;                   u = unit - U_F256; KS = 1; Klog = 28;  rs = 28;  }
  else if (unit < U_W2_0) { W = w1;                     u = unit - U_W1_0; KS = 8; Klog = 256; rs = 256; }
  else if (unit < U_W3_0) { W = w2;                     u = unit - U_W2_0; KS = 2; Klog = 64;  rs = 64;  }
  else if (unit < U_W1_1) { W = w3;                     u = unit - U_W3_0; KS = 4; Klog = 128; rs = 128; }
  else if (unit < U_W2_1) { W = w1 + 64 * 256;          u = unit - U_W1_1; KS = 4; Klog = 128; rs = 256; }
  else if (unit < U_W3_1) { W = w2 + 128 * 64;          u = unit - U_W2_1; KS = 2; Klog = 64;  rs = 64;  }
  else if (unit < U_W1_2) { W = w3 + 128 * 128;         u = unit - U_W3_1; KS = 4; Klog = 128; rs = 128; }
  else if (unit < U_W2_2) { W = w1 + 2 * 64 * 256;      u = unit - U_W1_2; KS = 4; Klog = 128; rs = 256; }
  else if (unit < U_W3_2) { W = w2 + 2 * 128 * 64;      u = unit - U_W2_2; KS = 2; Klog = 64;  rs = 64;  }
  else if (unit < U_O1)   { W = w3 + 2 * 128 * 128;     u = unit - U_W3_2; KS = 4; Klog = 128; rs = 128; }
  else if (unit < U_O2)   { W = wo1;                    u = unit - U_O1;   KS = 4; Klog = 128; rs = 256; }
  else                    { W = wo2;                    u = unit - U_O2;   KS = 4; Klog = 128; rs = 128; }
  const int nt = u / KS, ks = u % KS;
  const int n = nt * 16 + (lane & 15);
  const int k0 = ks * 32 + (lane >> 4) * 8;
  unsigned hiD[4], loD[4];
#pragma unroll
  for (int d = 0; d < 4; ++d) {
    unsigned hu[2], lu[2];
#pragma unroll
    for (int e = 0; e < 2; ++e) {
      const int k = k0 + d * 2 + e;
      float v = (k < Klog) ? W[(size_t)n * rs + k] : 0.f;
      unsigned uv = __float_as_uint(v);
      unsigned hm = uv & 0xFFFF0000u;
      float lo = v - __uint_as_float(hm);
      hu[e] = hm >> 16;
      lu[e] = __float_as_uint(lo) >> 16;
    }
    hiD[d] = hu[0] | (hu[1] << 16);
    loD[d] = lu[0] | (lu[1] << 16);
  }
  unsigned* dst = arena + ((size_t)unit * 64 + lane) * 8;
  *reinterpret_cast<uint4*>(dst)     = make_uint4(hiD[0], hiD[1], hiD[2], hiD[3]);
  *reinterpret_cast<uint4*>(dst + 4) = make_uint4(loD[0], loD[1], loD[2], loD[3]);
}

// ---- per-batch poolc table: 64-way max over block partials, then W[:,128:]*pool
template<int O>
__global__ void __launch_bounds__(1024) pool_reduce_kern(
    const unsigned* __restrict__ part, const float* __restrict__ W,
    const float* __restrict__ bias, float* __restrict__ poolc_g) {
  __shared__ float pfL[2048];        // [ch][cl] = ch*16+cl
  __shared__ float Wl[O * 129];
  const int tid = threadIdx.x;
  const int b = blockIdx.x;
  for (int i = tid; i < 2048; i += 1024) {
    float m = 0.f;
    const unsigned* pp = part + (size_t)(b * 64) * 2048 + i;
    for (int blk = 0; blk < 64; ++blk) m = fmaxf(m, __uint_as_float(pp[(size_t)blk * 2048]));
    pfL[i] = m;
  }
  for (int i = tid; i < O * 128; i += 1024) {
    const int o = i >> 7, k = i & 127;
    Wl[o * 129 + k] = W[o * 256 + 128 + k];
  }
  __syncthreads();
  constexpr int SH = (O == 64) ? 6 : 7;
  for (int e = tid; e < O * 16; e += 1024) {
    const int o = e & (O - 1);
    const int cl = e >> SH;
    float s = bias[o];
    const float* wr = &Wl[o * 129];
    const float* pr = &pfL[cl];
#pragma unroll 4
    for (int k = 0; k < 128; ++k) s = fmaf(wr[k], pr[k * 16], s);
    poolc_g[(size_t)b * (O * 16) + o * 16 + cl] = s;
  }
}

// ---- Stage 0: x -> f256 -> f64(w1[0]) -> f128(w2[0], pooled) -> f3_0(w3[0])
__global__ void __launch_bounds__(TPB, 4) k0_kern(
    const float* __restrict__ x, const int* __restrict__ cls,
    const float* __restrict__ b_in, const float* __restrict__ b1,
    const float* __restrict__ b2, const float* __restrict__ b3,
    const unsigned* __restrict__ arena,
    unsigned* __restrict__ f3g, unsigned* __restrict__ part0) {
  __shared__ short Fhi[PT * FSB], Flo[PT * FSB];
  __shared__ short XA[PT * ASB * 2];               // x planes alias A64 planes
  __shared__ unsigned pool_s[128 * NC];
  short* Xhi = XA;  short* Xlo = XA + PT * XSB;
  short* Ahi = XA;  short* Alo = XA + PT * ASB;
  const int tid = threadIdx.x;
  const int lane = tid & 63, w = tid >> 6, l15 = lane & 15, quad = lane >> 4;
  const int Nt1 = w & 3, mh = w >> 2;
  for (int i = tid; i < 128 * NC; i += TPB) pool_s[i] = 0u;

  float biH[2];
#pragma unroll
  for (int c = 0; c < 2; ++c) biH[c] = b_in[c * 128 + w * 16 + l15];
  const float b1H = b1[Nt1 * 16 + l15];
  const float b2H = b2[w * 16 + l15];
  const float b3H = b3[w * 16 + l15];
  const int n1 = Nt1 * 16 + l15;
  const int n2 = w * 16 + l15;
  const int xpt = (tid < 448) ? tid / 7 : 0;
  const int xc4 = (tid < 448) ? (tid - xpt * 7) * 4 : 0;

  for (int t = 0; t < TILES; ++t) {
    const int tile0 = (blockIdx.x * TILES + t) * PT;
    if (tid < 448) {   // stage x hi/lo
      const f32x4v v = __builtin_nontemporal_load(
          reinterpret_cast<const f32x4v*>(x + (size_t)(tile0 + xpt) * 28 + xc4));
      unsigned h0 = __float_as_uint(v.x) & 0xFFFF0000u, h1 = __float_as_uint(v.y) & 0xFFFF0000u;
      unsigned h2 = __float_as_uint(v.z) & 0xFFFF0000u, h3 = __float_as_uint(v.w) & 0xFFFF0000u;
      uint2 hd, ld;
      hd.x = (h0 >> 16) | h1;
      hd.y = (h2 >> 16) | h3;
      ld.x = (__float_as_uint(v.x - __uint_as_float(h0)) >> 16) |
             (__float_as_uint(v.y - __uint_as_float(h1)) & 0xFFFF0000u);
      ld.y = (__float_as_uint(v.z - __uint_as_float(h2)) >> 16) |
             (__float_as_uint(v.w - __uint_as_float(h3)) & 0xFFFF0000u);
      *reinterpret_cast<uint2*>(&Xhi[xpt * XSB + xc4]) = hd;
      *reinterpret_cast<uint2*>(&Xlo[xpt * XSB + xc4]) = ld;
    } else {           // zero k pads 28..31 (region aliased by A64 last tile)
      const int p = tid - 448;
      *reinterpret_cast<uint2*>(&Xhi[p * XSB + 28]) = make_uint2(0u, 0u);
      *reinterpret_cast<uint2*>(&Xlo[p * XSB + 28]) = make_uint2(0u, 0u);
    }
    int clP[4][4];
#pragma unroll
    for (int Mt = 0; Mt < 4; ++Mt) {
      int4 v = *reinterpret_cast<const int4*>(cls + tile0 + Mt * 16 + quad * 4);
      clP[Mt][0] = v.x; clP[Mt][1] = v.y; clP[Mt][2] = v.z; clP[Mt][3] = v.w;
    }
    __syncthreads();   // B1
    f32x4 a1[2];
#pragma unroll
    for (int m = 0; m < 2; ++m) a1[m] = {b1H, b1H, b1H, b1H};
#pragma unroll 1
    for (int c = 0; c < 2; ++c) {
      // f256 chunk c: wave owns 16 channels (nt = c*8+w), all 4 Mt
      f32x4 f6[4];
#pragma unroll
      for (int Mt = 0; Mt < 4; ++Mt) f6[Mt] = {biH[c], biH[c], biH[c], biH[c]};
      {
        bf16x8 bh, bl;
        bfrag(arena, U_F256 + c * 8 + w, bh, bl);
#pragma unroll
        for (int Mt = 0; Mt < 4; ++Mt) {
          const bf16x8 xah = afrag(Xhi, XSB, Mt, 0), xal = afrag(Xlo, XSB, Mt, 0);
          f6[Mt] = MFMA16(xal, bh, MFMA16(xah, bl, MFMA16(xah, bh, f6[Mt])));
        }
      }
#pragma unroll
      for (int Mt = 0; Mt < 4; ++Mt)
        store_planes(Fhi, Flo, FSB, Mt, n2, relu4(f6[Mt]));
      __syncthreads();   // B2 / B4: chunk staged, X reads done
#pragma unroll
      for (int ks = 0; ks < 4; ++ks) {
        bf16x8 bh, bl;
        bfrag(arena, U_W1_0 + Nt1 * 8 + c * 4 + ks, bh, bl);
#pragma unroll
        for (int m = 0; m < 2; ++m) {
          const bf16x8 ah = afrag(Fhi, FSB, mh * 2 + m, ks), al = afrag(Flo, FSB, mh * 2 + m, ks);
          a1[m] = MFMA16(al, bh, MFMA16(ah, bl, MFMA16(ah, bh, a1[m])));
        }
      }
      if (c == 1) {      // A64 write into XA: all X reads done (post-B4)
#pragma unroll
        for (int m = 0; m < 2; ++m)
          store_planes(Ahi, Alo, ASB, mh * 2 + m, n1, relu4(a1[m]));
      }
      __syncthreads();   // B3 / B5: chunk F-reads done (c=1: A staged)
    }
    // w2: wave owns 16 of 128 out, K=64, all Mt
    f32x4 f2[4];
#pragma unroll
    for (int Mt = 0; Mt < 4; ++Mt) f2[Mt] = {b2H, b2H, b2H, b2H};
#pragma unroll
    for (int ks = 0; ks < 2; ++ks) {
      bf16x8 bh, bl;
      bfrag(arena, U_W2_0 + w * 2 + ks, bh, bl);
#pragma unroll
      for (int Mt = 0; Mt < 4; ++Mt) {
        const bf16x8 ah = afrag(Ahi, ASB, Mt, ks), al = afrag(Alo, ASB, Mt, ks);
        f2[Mt] = MFMA16(al, bh, MFMA16(ah, bl, MFMA16(ah, bh, f2[Mt])));
      }
    }
#pragma unroll
    for (int Mt = 0; Mt < 4; ++Mt) {
      f32x4 d = relu4(f2[Mt]);
#pragma unroll
      for (int r = 0; r < 4; ++r)
        atomicMax(&pool_s[n2 * NC + clP[Mt][r]], __float_as_uint(d[r]));
      store_planes(Fhi, Flo, FSB, Mt, n2, d);   // F w1-readers done at B5
    }
    __syncthreads();   // B6: f128 staged
    // w3: wave owns 16 of 128 out, K=128, all Mt
    f32x4 f3a[4];
#pragma unroll
    for (int Mt = 0; Mt < 4; ++Mt) f3a[Mt] = {b3H, b3H, b3H, b3H};
#pragma unroll
    for (int ks = 0; ks < 4; ++ks) {
      bf16x8 bh, bl;
      bfrag(arena, U_W3_0 + w * 4 + ks, bh, bl);
#pragma unroll
      for (int Mt = 0; Mt < 4; ++Mt) {
        const bf16x8 ah = afrag(Fhi, FSB, Mt, ks), al = afrag(Flo, FSB, Mt, ks);
        f3a[Mt] = MFMA16(al, bh, MFMA16(ah, bl, MFMA16(ah, bh, f3a[Mt])));
      }
    }
    __syncthreads();   // B7: all w3 F-reads done
#pragma unroll
    for (int Mt = 0; Mt < 4; ++Mt)
      store_planes(Fhi, Flo, FSB, Mt, n2, relu4(f3a[Mt]));
    __syncthreads();   // B8: f3 planes staged
    write_f3(f3g, tile0, Fhi, Flo, tid);
    // no end barrier: next x-stage writes XA (readers fenced by B6);
    // next F-writes happen post-next-B1; pack-reads precede next B1.
  }
  for (int i = tid; i < 128 * NC; i += TPB)
    part0[(size_t)blockIdx.x * 2048 + i] = pool_s[i];   // plain store (no atomics)
}

// ---- Stages 1,2: f3 -> f64(w1+poolc) -> f128(w2, pooled) -> f3'(w3)
__global__ void __launch_bounds__(TPB, 4) kmid_kern(
    unsigned* __restrict__ f3g, const unsigned* __restrict__ arena,
    const float* __restrict__ poolc_g, unsigned* __restrict__ part_cur,
    const int* __restrict__ clg, const int* __restrict__ clp,
    const float* __restrict__ b2s, const float* __restrict__ b3s,
    int uW1, int uW2, int uW3) {
  __shared__ short Fhi[PT * FSB], Flo[PT * FSB];
  __shared__ short Ahi[PT * ASB], Alo[PT * ASB];
  __shared__ unsigned pool_s[128 * NC];
  const int tid = threadIdx.x;
  const int lane = tid & 63, w = tid >> 6, l15 = lane & 15, quad = lane >> 4;
  const int b = blockIdx.x >> 6;
  const int Nt1 = w & 3, mh = w >> 2;
  for (int i = tid; i < 128 * NC; i += TPB) pool_s[i] = 0u;
  const float b2H = b2s[w * 16 + l15];
  const float b3H = b3s[w * 16 + l15];
  const int n1 = Nt1 * 16 + l15;
  const int n2 = w * 16 + l15;

  for (int t = 0; t < TILES; ++t) {
    const int tile0 = (blockIdx.x * TILES + t) * PT;
    stage_f3(f3g, tile0, Fhi, Flo, tid);
    int clG[2][4], clP[4][4];
#pragma unroll
    for (int m = 0; m < 2; ++m) {
      int4 v = *reinterpret_cast<const int4*>(clg + tile0 + (mh * 2 + m) * 16 + quad * 4);
      clG[m][0] = v.x; clG[m][1] = v.y; clG[m][2] = v.z; clG[m][3] = v.w;
    }
#pragma unroll
    for (int Mt = 0; Mt < 4; ++Mt) {
      int4 v = *reinterpret_cast<const int4*>(clp + tile0 + Mt * 16 + quad * 4);
      clP[Mt][0] = v.x; clP[Mt][1] = v.y; clP[Mt][2] = v.z; clP[Mt][3] = v.w;
    }
    __syncthreads();   // B1: staged
    // w1: wave owns 16 of 64 out (Nt1), K=128, Mt = mh*2+m
    f32x4 a1[2];
#pragma unroll
    for (int m = 0; m < 2; ++m)
#pragma unroll
      for (int r = 0; r < 4; ++r)
        a1[m][r] = poolc_g[(size_t)b * 1024 + n1 * 16 + clG[m][r]];
#pragma unroll
    for (int ks = 0; ks < 4; ++ks) {
      bf16x8 bh, bl;
      bfrag(arena, uW1 + Nt1 * 4 + ks, bh, bl);
#pragma unroll
      for (int m = 0; m < 2; ++m) {
        const bf16x8 ah = afrag(Fhi, FSB, mh * 2 + m, ks), al = afrag(Flo, FSB, mh * 2 + m, ks);
        a1[m] = MFMA16(al, bh, MFMA16(ah, bl, MFMA16(ah, bh, a1[m])));
      }
    }
#pragma unroll
    for (int m = 0; m < 2; ++m)
      store_planes(Ahi, Alo, ASB, mh * 2 + m, n1, relu4(a1[m]));
    __syncthreads();   // B2: A64 staged
    // w2: wave owns 16 of 128 out, K=64, all Mt
    f32x4 f2[4];
#pragma unroll
    for (int Mt = 0; Mt < 4; ++Mt) f2[Mt] = {b2H, b2H, b2H, b2H};
#pragma unroll
    for (int ks = 0; ks < 2; ++ks) {
      bf16x8 bh, bl;
      bfrag(arena, uW2 + w * 2 + ks, bh, bl);
#pragma unroll
      for (int Mt = 0; Mt < 4; ++Mt) {
        const bf16x8 ah = afrag(Ahi, ASB, Mt, ks), al = afrag(Alo, ASB, Mt, ks);
        f2[Mt] = MFMA16(al, bh, MFMA16(ah, bl, MFMA16(ah, bh, f2[Mt])));
      }
    }
#pragma unroll
    for (int Mt = 0; Mt < 4; ++Mt) {
      f32x4 d = relu4(f2[Mt]);
#pragma unroll
      for (int r = 0; r < 4; ++r)
        atomicMax(&pool_s[n2 * NC + clP[Mt][r]], __float_as_uint(d[r]));
      store_planes(Fhi, Flo, FSB, Mt, n2, d);   // F w1-readers done at B2
    }
    __syncthreads();   // B3: f128 staged
    // w3: wave owns 16 of 128 out, K=128, all Mt
    f32x4 f3a[4];
#pragma unroll
    for (int Mt = 0; Mt < 4; ++Mt) f3a[Mt] = {b3H, b3H, b3H, b3H};
#pragma unroll
    for (int ks = 0; ks < 4; ++ks) {
      bf16x8 bh, bl;
      bfrag(arena, uW3 + w * 4 + ks, bh, bl);
#pragma unroll
      for (int Mt = 0; Mt < 4; ++Mt) {
        const bf16x8 ah = afrag(Fhi, FSB, Mt, ks), al = afrag(Flo, FSB, Mt, ks);
        f3a[Mt] = MFMA16(al, bh, MFMA16(ah, bl, MFMA16(ah, bh, f3a[Mt])));
      }
    }
    __syncthreads();   // B4: all w3 F-reads done
#pragma unroll
    for (int Mt = 0; Mt < 4; ++Mt)
      store_planes(Fhi, Flo, FSB, Mt, n2, relu4(f3a[Mt]));
    __syncthreads();   // B5: f3 planes staged
    write_f3(f3g, tile0, Fhi, Flo, tid);
    __syncthreads();   // B6: pack-reads done before next stage-in overwrite
  }
  for (int i = tid; i < 128 * NC; i += TPB)
    part_cur[(size_t)blockIdx.x * 2048 + i] = pool_s[i];   // plain store
}

// ---- Head: f3_2 -> o1(wo1+poolco) -> o2(wo2) -> global max
__global__ void __launch_bounds__(TPB, 4) k3_kern(
    const unsigned* __restrict__ f3g, const unsigned* __restrict__ arena,
    const float* __restrict__ poolco_g, const int* __restrict__ clg,
    const float* __restrict__ bo2, unsigned* __restrict__ out) {
  __shared__ short Fhi[PT * FSB], Flo[PT * FSB];
  const int tid = threadIdx.x;
  const int lane = tid & 63, w = tid >> 6, l15 = lane & 15, quad = lane >> 4;
  const int b = blockIdx.x >> 6;
  const float bo2H = bo2[w * 16 + l15];
  const int n2 = w * 16 + l15;
  float omax = 0.f;

  for (int t = 0; t < TILES; ++t) {
    const int tile0 = (blockIdx.x * TILES + t) * PT;
    stage_f3(f3g, tile0, Fhi, Flo, tid);
    int clA[4][4];
#pragma unroll
    for (int Mt = 0; Mt < 4; ++Mt) {
      int4 v = *reinterpret_cast<const int4*>(clg + tile0 + Mt * 16 + quad * 4);
      clA[Mt][0] = v.x; clA[Mt][1] = v.y; clA[Mt][2] = v.z; clA[Mt][3] = v.w;
    }
    __syncthreads();   // B1
    f32x4 o1a[4];
#pragma unroll
    for (int Mt = 0; Mt < 4; ++Mt) {
      const float* pcb = poolco_g + (size_t)b * 2048 + n2 * 16;
      o1a[Mt][0] = pcb[clA[Mt][0]]; o1a[Mt][1] = pcb[clA[Mt][1]];
      o1a[Mt][2] = pcb[clA[Mt][2]]; o1a[Mt][3] = pcb[clA[Mt][3]];
    }
#pragma unroll
    for (int ks = 0; ks < 4; ++ks) {
      bf16x8 bh, bl;
      bfrag(arena, U_O1 + w * 4 + ks, bh, bl);
#pragma unroll
      for (int Mt = 0; Mt < 4; ++Mt) {
        const bf16x8 ah = afrag(Fhi, FSB, Mt, ks), al = afrag(Flo, FSB, Mt, ks);
        o1a[Mt] = MFMA16(al, bh, MFMA16(ah, bl, MFMA16(ah, bh, o1a[Mt])));
      }
    }
    __syncthreads();   // B2: o1 F-reads done
#pragma unroll
    for (int Mt = 0; Mt < 4; ++Mt)
      store_planes(Fhi, Flo, FSB, Mt, n2, relu4(o1a[Mt]));
    __syncthreads();   // B3: o1 staged
    f32x4 o2a[4];
#pragma unroll
    for (int Mt = 0; Mt < 4; ++Mt) o2a[Mt] = {bo2H, bo2H, bo2H, bo2H};
#pragma unroll
    for (int ks = 0; ks < 4; ++ks) {
      bf16x8 bh, bl;
      bfrag(arena, U_O2 + w * 4 + ks, bh, bl);
#pragma unroll
      for (int Mt = 0; Mt < 4; ++Mt) {
        const bf16x8 ah = afrag(Fhi, FSB, Mt, ks), al = afrag(Flo, FSB, Mt, ks);
        o2a[Mt] = MFMA16(al, bh, MFMA16(ah, bl, MFMA16(ah, bh, o2a[Mt])));
      }
    }
#pragma unroll
    for (int Mt = 0; Mt < 4; ++Mt) {
      f32x4 d = relu4(o2a[Mt]);
      omax = fmaxf(omax, fmaxf(fmaxf(d[0], d[1]), fmaxf(d[2], d[3])));
    }
    __syncthreads();   // B4: o2 F-reads done before next stage-in
  }
  omax = fmaxf(omax, __shfl_xor(omax, 16));
  omax = fmaxf(omax, __shfl_xor(omax, 32));
  if (lane < 16)
    atomicMax(&out[b * 128 + w * 16 + lane], __float_as_uint(omax));
}

extern "C" void kernel_launch(void* const* d_in, const int* in_sizes, int n_in,
                              void* d_out, int out_size, void* d_ws, size_t ws_size,
                              hipStream_t stream) {
  const float* x    = (const float*)d_in[0];
  const int*   cls  = (const int*)d_in[1];
  const float* w_in = (const float*)d_in[2];
  const float* b_in = (const float*)d_in[3];
  const float* w1   = (const float*)d_in[4];
  const float* b1   = (const float*)d_in[5];
  const float* w2   = (const float*)d_in[6];
  const float* b2   = (const float*)d_in[7];
  const float* w3   = (const float*)d_in[8];
  const float* b3   = (const float*)d_in[9];
  const float* wo1  = (const float*)d_in[10];
  const float* bo1  = (const float*)d_in[11];
  const float* wo2  = (const float*)d_in[12];
  const float* bo2  = (const float*)d_in[13];

  char* ws = (char*)d_ws;
  unsigned* f3g = (unsigned*)ws;                            // 64 MB packed hi|lo
  unsigned* part0 = (unsigned*)(ws + ((size_t)64 << 20));   // 3 x 4 MB (per-block)
  unsigned* part1 = part0 + (size_t)NBLK * 2048;
  unsigned* part2 = part1 + (size_t)NBLK * 2048;
  float* poolc1 = (float*)(part2 + (size_t)NBLK * 2048);    // 8*1024
  float* poolc2 = poolc1 + 8 * 1024;
  float* poolco = poolc2 + 8 * 1024;                        // 8*2048
  unsigned* arena = (unsigned*)(poolco + 8 * 2048);         // 288*512 dwords

  hipMemsetAsync(d_out, 0, 1024 * sizeof(float), stream);

  prep_frags<<<N_UNITS, 64, 0, stream>>>(w_in, w1, w2, w3, wo1, wo2, arena);
  k0_kern<<<NBLK, TPB, 0, stream>>>(x, cls, b_in, b1, b2, b3, arena, f3g, part0);
  pool_reduce_kern<64><<<8, 1024, 0, stream>>>(part0, w1 + (size_t)64 * 256, b1 + 64, poolc1);
  kmid_kern<<<NBLK, TPB, 0, stream>>>(f3g, arena, poolc1, part1, cls, cls + NPTS,
                                      b2 + 128, b3 + 128, U_W1_1, U_W2_1, U_W3_1);
  pool_reduce_kern<64><<<8, 1024, 0, stream>>>(part1, w1 + (size_t)2 * 64 * 256, b1 + 128, poolc2);
  kmid_kern<<<NBLK, TPB, 0, stream>>>(f3g, arena, poolc2, part2, cls + NPTS, cls + 2 * NPTS,
                                      b2 + 256, b3 + 256, U_W1_2, U_W2_2, U_W3_2);
  pool_reduce_kern<128><<<8, 1024, 0, stream>>>(part2, wo1, bo1, poolco);
  k3_kern<<<NBLK, TPB, 0, stream>>>(f3g, arena, poolco, cls + 2 * NPTS, bo2, (unsigned*)d_out);
}

// Round 13
// 422.847 us; speedup vs baseline: 1.2483x; 1.1288x over previous
//
#include <hip/hip_runtime.h>

// LapCluster MI355X — round 13: r10 base + plain write_f3 stores + packed cluster ids.
// r12 post-mortem: atomics were L2-resident (FETCH/WRITE identical with/without)
// — r11's "atomics cost 64+64MB" theory was WRONG. r12's 61us regression was the
// strided 64-way pool_reduce (8 blocks x 64 serial 8KB-stride loads). Revert to
// r10 (416us best). Remaining WRITE excess (124 vs 68MB true, no spills at
// VGPR=64/128 budget) is now pinned by elimination on __builtin_nontemporal_store
// in write_f3 (write-through + later writeback ~= 2x stream). Delta (a): plain
// stores in write_f3. Delta (b): cluster ids nibble-packed (4 ids/u32) to cut
// live VGPRs. Everything else identical to r10.
// Math: 16x16x32 bf16 MFMA, 3-term split (AhBh+AhBl+AlBh).
// A[m=lane&15][k=quad*8+j], B[k=quad*8+j][n=lane&15], D[m=quad*4+r][n=lane&15].
// Pool trick: W*[f3,pool] = W[:,:128]*f3 + poolc[o][cluster]; clusters in
// [0,16); ReLU>=0 -> float-bit max exact.

typedef __attribute__((ext_vector_type(8))) short bf16x8;
typedef __attribute__((ext_vector_type(4))) float f32x4;
typedef __attribute__((ext_vector_type(4))) unsigned u32x4;
typedef __attribute__((ext_vector_type(4))) float f32x4v;

#define MFMA16(a, b, c) __builtin_amdgcn_mfma_f32_16x16x32_bf16((a), (b), (c), 0, 0, 0)

#define TPB 512
#define PT 64
#define NPTS 131072
#define NC 16
#define TILES 4
#define NBLK 512         // 64 blocks/batch

#define FSB 136          // 128-ch plane stride (bf16 units)
#define ASB 72           // 64-ch plane stride
#define XSB 40           // 32-ch (padded x) plane stride

// frag arena units (1 unit = 64 lanes * 8 dwords: [0..3]=hi frag, [4..7]=lo)
#define U_F256 0
#define U_W1_0 16
#define U_W2_0 48
#define U_W3_0 64
#define U_W1_1 96
#define U_W2_1 112
#define U_W3_1 128
#define U_W1_2 160
#define U_W2_2 176
#define U_W3_2 192
#define U_O1   224
#define U_O2   256
#define N_UNITS 288

__device__ __forceinline__ f32x4 relu4(f32x4 a) {
#pragma unroll
  for (int r = 0; r < 4; ++r) a[r] = fmaxf(a[r], 0.f);
  return a;
}

__device__ __forceinline__ unsigned pack4(int4 v) {
  return (unsigned)v.x | ((unsigned)v.y << 4) | ((unsigned)v.z << 8) | ((unsigned)v.w << 12);
}

__device__ __forceinline__ bf16x8 afrag(const short* plane, int stride, int mt, int ks) {
  const int lane = threadIdx.x & 63;
  return *reinterpret_cast<const bf16x8*>(
      plane + (mt * 16 + (lane & 15)) * stride + ks * 32 + (lane >> 4) * 8);
}

__device__ __forceinline__ void bfrag(const unsigned* __restrict__ arena, int unit,
                                      bf16x8& h, bf16x8& l) {
  const bf16x8* p = reinterpret_cast<const bf16x8*>(
      arena + ((size_t)unit * 64 + (threadIdx.x & 63)) * 8);
  h = p[0];
  l = p[1];
}

// write already-relu'd D (4 regs = pts mt*16 + quad*4 + r) as hi/lo bf16
__device__ __forceinline__ void store_planes(short* hp, short* lp, int stride,
                                             int mt, int n, f32x4 d) {
  const int m0 = mt * 16 + ((threadIdx.x & 63) >> 4) * 4;
#pragma unroll
  for (int r = 0; r < 4; ++r) {
    unsigned uv = __float_as_uint(d[r]);
    unsigned hm = uv & 0xFFFF0000u;
    float lo = d[r] - __uint_as_float(hm);
    hp[(m0 + r) * stride + n] = (short)(hm >> 16);
    lp[(m0 + r) * stride + n] = (short)(__float_as_uint(lo) >> 16);
  }
}

// unpack a prefetched packed-f3 u32x4 into hi/lo LDS planes
__device__ __forceinline__ void unpack_to_planes(u32x4 p, int idx, short* Fhi, short* Flo) {
  const int pt = idx >> 5, c4 = (idx & 31) * 4;
  uint2 hd, ld;
  hd.x = (p.y & 0xFFFF0000u) | (p.x >> 16);
  hd.y = (p.w & 0xFFFF0000u) | (p.z >> 16);
  ld.x = (p.y << 16) | (p.x & 0xFFFFu);
  ld.y = (p.w << 16) | (p.z & 0xFFFFu);
  *reinterpret_cast<uint2*>(&Fhi[pt * FSB + c4]) = hd;
  *reinterpret_cast<uint2*>(&Flo[pt * FSB + c4]) = ld;
}

// coalesced pack-write: hi/lo planes -> packed f3 global (PLAIN stores)
__device__ __forceinline__ void write_f3(unsigned* __restrict__ f3g, int tile0,
                                         const short* Fhi, const short* Flo, int tid) {
  u32x4* dst = reinterpret_cast<u32x4*>(f3g + (size_t)tile0 * 128);
#pragma unroll
  for (int rr = 0; rr < 4; ++rr) {
    const int idx = rr * TPB + tid;
    const int pt = idx >> 5, c4 = (idx & 31) * 4;
    const uint2 hd = *reinterpret_cast<const uint2*>(&Fhi[pt * FSB + c4]);
    const uint2 ld = *reinterpret_cast<const uint2*>(&Flo[pt * FSB + c4]);
    u32x4 p;
    p.x = (hd.x << 16) | (ld.x & 0xFFFFu);
    p.y = (hd.x & 0xFFFF0000u) | (ld.x >> 16);
    p.z = (hd.y << 16) | (ld.y & 0xFFFFu);
    p.w = (hd.y & 0xFFFF0000u) | (ld.y >> 16);
    dst[idx] = p;   // plain store (nt removed)
  }
}

// ---- prep: split weights into fragment-ordered hi/lo bf16 arenas
__global__ void __launch_bounds__(64) prep_frags(
    const float* __restrict__ w_in, const float* __restrict__ w1,
    const float* __restrict__ w2, const float* __restrict__ w3,
    const float* __restrict__ wo1, const float* __restrict__ wo2,
    unsigned* __restrict__ arena) {
  const int unit = blockIdx.x;
  const int lane = threadIdx.x;
  const float* W; int KS, Klog, rs, u;
  if (unit < U_W1_0)      { W = w_in;                   u = unit - U_F256; KS = 1; Klog = 28;  rs = 28;  }
  else if (unit < U_W2_0) { W = w1;                     u = unit - U_W1_0; KS = 8; Klog = 256; rs = 256; }
  else if (unit < U_W3_0) { W = w2;                     u = unit - U_W2_0; KS = 2; Klog = 64;  rs = 64;  }
  else if (unit < U_W1_1) { W = w3;                     u = unit - U_W3_0; KS = 4; Klog = 128; rs = 128; }
  else if (unit < U_W2_1) { W = w1 + 64 * 256;          u = unit - U_W1_1; KS = 4; Klog = 128; rs = 256; }
  else if (unit < U_W3_1) { W = w2 + 128 * 64;          u = unit - U_W2_1; KS = 2; Klog = 64;  rs = 64;  }
  else if (unit < U_W1_2) { W = w3 + 128 * 128;         u = unit - U_W3_1; KS = 4; Klog = 128; rs = 128; }
  else if (unit < U_W2_2) { W = w1 + 2 * 64 * 256;      u = unit - U_W1_2; KS = 4; Klog = 128; rs = 256; }
  else if (unit < U_W3_2) { W = w2 + 2 * 128 * 64;      u = unit - U_W2_2; KS = 2; Klog = 64;  rs = 64;  }
  else if (unit < U_O1)   { W = w3 + 2 * 128 * 128;     u = unit - U_W3_2; KS = 4; Klog = 128; rs = 128; }
  else if (unit < U_O2)   { W = wo1;                    u = unit - U_O1;   KS = 4; Klog = 128; rs = 256; }
  else                    { W = wo2;                    u = unit - U_O2;   KS = 4; Klog = 128; rs = 128; }
  const int nt = u / KS, ks = u % KS;
  const int n = nt * 16 + (lane & 15);
  const int k0 = ks * 32 + (lane >> 4) * 8;
  unsigned hiD[4], loD[4];
#pragma unroll
  for (int d = 0; d < 4; ++d) {
    unsigned hu[2], lu[2];
#pragma unroll
    for (int e = 0; e < 2; ++e) {
      const int k = k0 + d * 2 + e;
      float v = (k < Klog) ? W[(size_t)n * rs + k] : 0.f;
      unsigned uv = __float_as_uint(v);
      unsigned hm = uv & 0xFFFF0000u;
      float lo = v - __uint_as_float(hm);
      hu[e] = hm >> 16;
      lu[e] = __float_as_uint(lo) >> 16;
    }
    hiD[d] = hu[0] | (hu[1] << 16);
    loD[d] = lu[0] | (lu[1] << 16);
  }
  unsigned* dst = arena + ((size_t)unit * 64 + lane) * 8;
  *reinterpret_cast<uint4*>(dst)     = make_uint4(hiD[0], hiD[1], hiD[2], hiD[3]);
  *reinterpret_cast<uint4*>(dst + 4) = make_uint4(loD[0], loD[1], loD[2], loD[3]);
}

// ---- per-batch poolc table (reads the atomically-maxed 8KB table)
template<int O>
__global__ void __launch_bounds__(1024) pool_reduce_kern(
    const unsigned* __restrict__ part, const float* __restrict__ W,
    const float* __restrict__ bias, float* __restrict__ poolc_g) {
  __shared__ float pfL[2048];
  __shared__ float Wl[O * 129];
  const int tid = threadIdx.x;
  const int b = blockIdx.x;
  for (int i = tid; i < 2048; i += 1024) pfL[i] = __uint_as_float(part[b * 2048 + i]);
  for (int i = tid; i < O * 128; i += 1024) {
    const int o = i >> 7, k = i & 127;
    Wl[o * 129 + k] = W[o * 256 + 128 + k];
  }
  __syncthreads();
  constexpr int SH = (O == 64) ? 6 : 7;
  for (int e = tid; e < O * 16; e += 1024) {
    const int o = e & (O - 1);
    const int cl = e >> SH;
    float s = bias[o];
    const float* wr = &Wl[o * 129];
    const float* pr = &pfL[cl];
#pragma unroll 4
    for (int k = 0; k < 128; ++k) s = fmaf(wr[k], pr[k * 16], s);
    poolc_g[(size_t)b * (O * 16) + o * 16 + cl] = s;
  }
}

// ---- Stage 0: x -> f256 -> f64(w1[0]) -> f128(w2[0], pooled) -> f3_0(w3[0])
__global__ void __launch_bounds__(TPB, 4) k0_kern(
    const float* __restrict__ x, const int* __restrict__ cls,
    const float* __restrict__ b_in, const float* __restrict__ b1,
    const float* __restrict__ b2, const float* __restrict__ b3,
    const unsigned* __restrict__ arena,
    unsigned* __restrict__ f3g, unsigned* __restrict__ part0) {
  __shared__ short Fhi[PT * FSB], Flo[PT * FSB];
  __shared__ short XA[PT * ASB * 2];               // x planes alias A64 planes
  __shared__ unsigned pool_s[128 * NC];
  short* Xhi = XA;  short* Xlo = XA + PT * XSB;
  short* Ahi = XA;  short* Alo = XA + PT * ASB;
  const int tid = threadIdx.x;
  const int lane = tid & 63, w = tid >> 6, l15 = lane & 15, quad = lane >> 4;
  const int b = blockIdx.x >> 6;
  const int Nt1 = w & 3, mh = w >> 2;
  for (int i = tid; i < 128 * NC; i += TPB) pool_s[i] = 0u;

  float biH[2];
#pragma unroll
  for (int c = 0; c < 2; ++c) biH[c] = b_in[c * 128 + w * 16 + l15];
  const float b1H = b1[Nt1 * 16 + l15];
  const float b2H = b2[w * 16 + l15];
  const float b3H = b3[w * 16 + l15];
  const int n1 = Nt1 * 16 + l15;
  const int n2 = w * 16 + l15;
  const int xpt = (tid < 448) ? tid / 7 : 0;
  const int xc4 = (tid < 448) ? (tid - xpt * 7) * 4 : 0;

  const int tb0 = blockIdx.x * TILES * PT;
  f32x4v xpre = {};
  if (tid < 448)
    xpre = *reinterpret_cast<const f32x4v*>(x + (size_t)(tb0 + xpt) * 28 + xc4);

  for (int t = 0; t < TILES; ++t) {
    const int tile0 = tb0 + t * PT;
    if (tid < 448) {   // stage prefetched x hi/lo
      const f32x4v v = xpre;
      unsigned h0 = __float_as_uint(v.x) & 0xFFFF0000u, h1 = __float_as_uint(v.y) & 0xFFFF0000u;
      unsigned h2 = __float_as_uint(v.z) & 0xFFFF0000u, h3 = __float_as_uint(v.w) & 0xFFFF0000u;
      uint2 hd, ld;
      hd.x = (h0 >> 16) | h1;
      hd.y = (h2 >> 16) | h3;
      ld.x = (__float_as_uint(v.x - __uint_as_float(h0)) >> 16) |
             (__float_as_uint(v.y - __uint_as_float(h1)) & 0xFFFF0000u);
      ld.y = (__float_as_uint(v.z - __uint_as_float(h2)) >> 16) |
             (__float_as_uint(v.w - __uint_as_float(h3)) & 0xFFFF0000u);
      *reinterpret_cast<uint2*>(&Xhi[xpt * XSB + xc4]) = hd;
      *reinterpret_cast<uint2*>(&Xlo[xpt * XSB + xc4]) = ld;
    } else {           // zero k pads 28..31 (region aliased by A64 last tile)
      const int p = tid - 448;
      *reinterpret_cast<uint2*>(&Xhi[p * XSB + 28]) = make_uint2(0u, 0u);
      *reinterpret_cast<uint2*>(&Xlo[p * XSB + 28]) = make_uint2(0u, 0u);
    }
    unsigned clPp[4];
#pragma unroll
    for (int Mt = 0; Mt < 4; ++Mt)
      clPp[Mt] = pack4(*reinterpret_cast<const int4*>(cls + tile0 + Mt * 16 + quad * 4));
    __syncthreads();   // B1
    if (t + 1 < TILES && tid < 448)
      xpre = *reinterpret_cast<const f32x4v*>(x + (size_t)(tile0 + PT + xpt) * 28 + xc4);
    f32x4 a1[2];
#pragma unroll
    for (int m = 0; m < 2; ++m) a1[m] = {b1H, b1H, b1H, b1H};
#pragma unroll 1
    for (int c = 0; c < 2; ++c) {
      // f256 chunk c: wave owns 16 channels (nt = c*8+w), all 4 Mt
      f32x4 f6[4];
#pragma unroll
      for (int Mt = 0; Mt < 4; ++Mt) f6[Mt] = {biH[c], biH[c], biH[c], biH[c]};
      {
        bf16x8 bh, bl;
        bfrag(arena, U_F256 + c * 8 + w, bh, bl);
#pragma unroll
        for (int Mt = 0; Mt < 4; ++Mt) {
          const bf16x8 xah = afrag(Xhi, XSB, Mt, 0), xal = afrag(Xlo, XSB, Mt, 0);
          f6[Mt] = MFMA16(xal, bh, MFMA16(xah, bl, MFMA16(xah, bh, f6[Mt])));
        }
      }
#pragma unroll
      for (int Mt = 0; Mt < 4; ++Mt)
        store_planes(Fhi, Flo, FSB, Mt, n2, relu4(f6[Mt]));
      __syncthreads();   // B2 / B4: chunk staged, X reads done
#pragma unroll
      for (int ks = 0; ks < 4; ++ks) {
        bf16x8 bh, bl;
        bfrag(arena, U_W1_0 + Nt1 * 8 + c * 4 + ks, bh, bl);
#pragma unroll
        for (int m = 0; m < 2; ++m) {
          const bf16x8 ah = afrag(Fhi, FSB, mh * 2 + m, ks), al = afrag(Flo, FSB, mh * 2 + m, ks);
          a1[m] = MFMA16(al, bh, MFMA16(ah, bl, MFMA16(ah, bh, a1[m])));
        }
      }
      if (c == 1) {      // A64 write into XA: all X reads done (post-B4)
#pragma unroll
        for (int m = 0; m < 2; ++m)
          store_planes(Ahi, Alo, ASB, mh * 2 + m, n1, relu4(a1[m]));
      }
      __syncthreads();   // B3 / B5: chunk F-reads done (c=1: A staged)
    }
    // w2: wave owns 16 of 128 out, K=64, all Mt
    f32x4 f2[4];
#pragma unroll
    for (int Mt = 0; Mt < 4; ++Mt) f2[Mt] = {b2H, b2H, b2H, b2H};
#pragma unroll
    for (int ks = 0; ks < 2; ++ks) {
      bf16x8 bh, bl;
      bfrag(arena, U_W2_0 + w * 2 + ks, bh, bl);
#pragma unroll
      for (int Mt = 0; Mt < 4; ++Mt) {
        const bf16x8 ah = afrag(Ahi, ASB, Mt, ks), al = afrag(Alo, ASB, Mt, ks);
        f2[Mt] = MFMA16(al, bh, MFMA16(ah, bl, MFMA16(ah, bh, f2[Mt])));
      }
    }
#pragma unroll
    for (int Mt = 0; Mt < 4; ++Mt) {
      f32x4 d = relu4(f2[Mt]);
#pragma unroll
      for (int r = 0; r < 4; ++r)
        atomicMax(&pool_s[n2 * NC + ((clPp[Mt] >> (4 * r)) & 15)], __float_as_uint(d[r]));
      store_planes(Fhi, Flo, FSB, Mt, n2, d);   // F w1-readers done at B5
    }
    __syncthreads();   // B6: f128 staged
    // w3: wave owns 16 of 128 out, K=128, all Mt
    f32x4 f3a[4];
#pragma unroll
    for (int Mt = 0; Mt < 4; ++Mt) f3a[Mt] = {b3H, b3H, b3H, b3H};
#pragma unroll
    for (int ks = 0; ks < 4; ++ks) {
      bf16x8 bh, bl;
      bfrag(arena, U_W3_0 + w * 4 + ks, bh, bl);
#pragma unroll
      for (int Mt = 0; Mt < 4; ++Mt) {
        const bf16x8 ah = afrag(Fhi, FSB, Mt, ks), al = afrag(Flo, FSB, Mt, ks);
        f3a[Mt] = MFMA16(al, bh, MFMA16(ah, bl, MFMA16(ah, bh, f3a[Mt])));
      }
    }
    __syncthreads();   // B7: all w3 F-reads done
#pragma unroll
    for (int Mt = 0; Mt < 4; ++Mt)
      store_planes(Fhi, Flo, FSB, Mt, n2, relu4(f3a[Mt]));
    __syncthreads();   // B8: f3 planes staged
    write_f3(f3g, tile0, Fhi, Flo, tid);
    // no end barrier: next x-stage writes XA (readers fenced by B6);
    // next F-writes happen post-next-B1; pack-reads precede next B1.
  }
  for (int i = tid; i < 128 * NC; i += TPB)
    atomicMax(&part0[(size_t)b * 2048 + i], pool_s[i]);
}

// ---- Stages 1,2: f3 -> f64(w1+poolc) -> f128(w2, pooled) -> f3'(w3)
__global__ void __launch_bounds__(TPB, 4) kmid_kern(
    unsigned* __restrict__ f3g, const unsigned* __restrict__ arena,
    const float* __restrict__ poolc_g, unsigned* __restrict__ part_cur,
    const int* __restrict__ clg, const int* __restrict__ clp,
    const float* __restrict__ b2s, const float* __restrict__ b3s,
    int uW1, int uW2, int uW3) {
  __shared__ short Fhi[PT * FSB], Flo[PT * FSB];
  __shared__ short Ahi[PT * ASB], Alo[PT * ASB];
  __shared__ unsigned pool_s[128 * NC];
  const int tid = threadIdx.x;
  const int lane = tid & 63, w = tid >> 6, l15 = lane & 15, quad = lane >> 4;
  const int b = blockIdx.x >> 6;
  const int Nt1 = w & 3, mh = w >> 2;
  for (int i = tid; i < 128 * NC; i += TPB) pool_s[i] = 0u;
  const float b2H = b2s[w * 16 + l15];
  const float b3H = b3s[w * 16 + l15];
  const int n1 = Nt1 * 16 + l15;
  const int n2 = w * 16 + l15;

  const int tb0 = blockIdx.x * TILES * PT;
  const u32x4* srcAll = reinterpret_cast<const u32x4*>(f3g);
  u32x4 p[4];
  unsigned cgp0, cgp1;
#pragma unroll
  for (int rr = 0; rr < 4; ++rr)
    p[rr] = srcAll[(size_t)tb0 * 32 + rr * TPB + tid];
  cgp0 = pack4(*reinterpret_cast<const int4*>(clg + tb0 + (mh * 2 + 0) * 16 + quad * 4));
  cgp1 = pack4(*reinterpret_cast<const int4*>(clg + tb0 + (mh * 2 + 1) * 16 + quad * 4));

  for (int t = 0; t < TILES; ++t) {
    const int tile0 = tb0 + t * PT;
#pragma unroll
    for (int rr = 0; rr < 4; ++rr) unpack_to_planes(p[rr], rr * TPB + tid, Fhi, Flo);
    unsigned clPp[4];
#pragma unroll
    for (int Mt = 0; Mt < 4; ++Mt)
      clPp[Mt] = pack4(*reinterpret_cast<const int4*>(clp + tile0 + Mt * 16 + quad * 4));
    const unsigned cgA = cgp0, cgB = cgp1;
    __syncthreads();   // B1: staged
    if (t + 1 < TILES) {
#pragma unroll
      for (int rr = 0; rr < 4; ++rr)
        p[rr] = srcAll[(size_t)(tile0 + PT) * 32 + rr * TPB + tid];
      cgp0 = pack4(*reinterpret_cast<const int4*>(clg + tile0 + PT + (mh * 2 + 0) * 16 + quad * 4));
      cgp1 = pack4(*reinterpret_cast<const int4*>(clg + tile0 + PT + (mh * 2 + 1) * 16 + quad * 4));
    }
    // w1: wave owns 16 of 64 out (Nt1), K=128, Mt = mh*2+m
    f32x4 a1[2];
    {
      const float* pcb = poolc_g + (size_t)b * 1024 + n1 * 16;
#pragma unroll
      for (int r = 0; r < 4; ++r) {
        a1[0][r] = pcb[(cgA >> (4 * r)) & 15];
        a1[1][r] = pcb[(cgB >> (4 * r)) & 15];
      }
    }
#pragma unroll
    for (int ks = 0; ks < 4; ++ks) {
      bf16x8 bh, bl;
      bfrag(arena, uW1 + Nt1 * 4 + ks, bh, bl);
#pragma unroll
      for (int m = 0; m < 2; ++m) {
        const bf16x8 ah = afrag(Fhi, FSB, mh * 2 + m, ks), al = afrag(Flo, FSB, mh * 2 + m, ks);
        a1[m] = MFMA16(al, bh, MFMA16(ah, bl, MFMA16(ah, bh, a1[m])));
      }
    }
#pragma unroll
    for (int m = 0; m < 2; ++m)
      store_planes(Ahi, Alo, ASB, mh * 2 + m, n1, relu4(a1[m]));
    __syncthreads();   // B2: A64 staged
    // w2: wave owns 16 of 128 out, K=64, all Mt
    f32x4 f2[4];
#pragma unroll
    for (int Mt = 0; Mt < 4; ++Mt) f2[Mt] = {b2H, b2H, b2H, b2H};
#pragma unroll
    for (int ks = 0; ks < 2; ++ks) {
      bf16x8 bh, bl;
      bfrag(arena, uW2 + w * 2 + ks, bh, bl);
#pragma unroll
      for (int Mt = 0; Mt < 4; ++Mt) {
        const bf16x8 ah = afrag(Ahi, ASB, Mt, ks), al = afrag(Alo, ASB, Mt, ks);
        f2[Mt] = MFMA16(al, bh, MFMA16(ah, bl, MFMA16(ah, bh, f2[Mt])));
      }
    }
#pragma unroll
    for (int Mt = 0; Mt < 4; ++Mt) {
      f32x4 d = relu4(f2[Mt]);
#pragma unroll
      for (int r = 0; r < 4; ++r)
        atomicMax(&pool_s[n2 * NC + ((clPp[Mt] >> (4 * r)) & 15)], __float_as_uint(d[r]));
      store_planes(Fhi, Flo, FSB, Mt, n2, d);   // F w1-readers done at B2
    }
    __syncthreads();   // B3: f128 staged
    // w3: wave owns 16 of 128 out, K=128, all Mt
    f32x4 f3a[4];
#pragma unroll
    for (int Mt = 0; Mt < 4; ++Mt) f3a[Mt] = {b3H, b3H, b3H, b3H};
#pragma unroll
    for (int ks = 0; ks < 4; ++ks) {
      bf16x8 bh, bl;
      bfrag(arena, uW3 + w * 4 + ks, bh, bl);
#pragma unroll
      for (int Mt = 0; Mt < 4; ++Mt) {
        const bf16x8 ah = afrag(Fhi, FSB, Mt, ks), al = afrag(Flo, FSB, Mt, ks);
        f3a[Mt] = MFMA16(al, bh, MFMA16(ah, bl, MFMA16(ah, bh, f3a[Mt])));
      }
    }
    __syncthreads();   // B4: all w3 F-reads done
#pragma unroll
    for (int Mt = 0; Mt < 4; ++Mt)
      store_planes(Fhi, Flo, FSB, Mt, n2, relu4(f3a[Mt]));
    __syncthreads();   // B5: f3 planes staged
    write_f3(f3g, tile0, Fhi, Flo, tid);
    __syncthreads();   // B6: pack-reads done before next stage-in overwrite
  }
  for (int i = tid; i < 128 * NC; i += TPB)
    atomicMax(&part_cur[(size_t)b * 2048 + i], pool_s[i]);
}

// ---- Head: f3_2 -> o1(wo1+poolco) -> o2(wo2) -> global max
__global__ void __launch_bounds__(TPB, 4) k3_kern(
    const unsigned* __restrict__ f3g, const unsigned* __restrict__ arena,
    const float* __restrict__ poolco_g, const int* __restrict__ clg,
    const float* __restrict__ bo2, unsigned* __restrict__ out) {
  __shared__ short Fhi[PT * FSB], Flo[PT * FSB];
  const int tid = threadIdx.x;
  const int lane = tid & 63, w = tid >> 6, l15 = lane & 15, quad = lane >> 4;
  const int b = blockIdx.x >> 6;
  const float bo2H = bo2[w * 16 + l15];
  const int n2 = w * 16 + l15;
  float omax = 0.f;

  const int tb0 = blockIdx.x * TILES * PT;
  const u32x4* srcAll = reinterpret_cast<const u32x4*>(f3g);
  u32x4 p[4];
#pragma unroll
  for (int rr = 0; rr < 4; ++rr)
    p[rr] = srcAll[(size_t)tb0 * 32 + rr * TPB + tid];

  for (int t = 0; t < TILES; ++t) {
    const int tile0 = tb0 + t * PT;
#pragma unroll
    for (int rr = 0; rr < 4; ++rr) unpack_to_planes(p[rr], rr * TPB + tid, Fhi, Flo);
    unsigned clAp[4];
#pragma unroll
    for (int Mt = 0; Mt < 4; ++Mt)
      clAp[Mt] = pack4(*reinterpret_cast<const int4*>(clg + tile0 + Mt * 16 + quad * 4));
    __syncthreads();   // B1
    if (t + 1 < TILES) {
#pragma unroll
      for (int rr = 0; rr < 4; ++rr)
        p[rr] = srcAll[(size_t)(tile0 + PT) * 32 + rr * TPB + tid];
    }
    f32x4 o1a[4];
#pragma unroll
    for (int Mt = 0; Mt < 4; ++Mt) {
      const float* pcb = poolco_g + (size_t)b * 2048 + n2 * 16;
#pragma unroll
      for (int r = 0; r < 4; ++r) o1a[Mt][r] = pcb[(clAp[Mt] >> (4 * r)) & 15];
    }
#pragma unroll
    for (int ks = 0; ks < 4; ++ks) {
      bf16x8 bh, bl;
      bfrag(arena, U_O1 + w * 4 + ks, bh, bl);
#pragma unroll
      for (int Mt = 0; Mt < 4; ++Mt) {
        const bf16x8 ah = afrag(Fhi, FSB, Mt, ks), al = afrag(Flo, FSB, Mt, ks);
        o1a[Mt] = MFMA16(al, bh, MFMA16(ah, bl, MFMA16(ah, bh, o1a[Mt])));
      }
    }
    __syncthreads();   // B2: o1 F-reads done
#pragma unroll
    for (int Mt = 0; Mt < 4; ++Mt)
      store_planes(Fhi, Flo, FSB, Mt, n2, relu4(o1a[Mt]));
    __syncthreads();   // B3: o1 staged
    f32x4 o2a[4];
#pragma unroll
    for (int Mt = 0; Mt < 4; ++Mt) o2a[Mt] = {bo2H, bo2H, bo2H, bo2H};
#pragma unroll
    for (int ks = 0; ks < 4; ++ks) {
      bf16x8 bh, bl;
      bfrag(arena, U_O2 + w * 4 + ks, bh, bl);
#pragma unroll
      for (int Mt = 0; Mt < 4; ++Mt) {
        const bf16x8 ah = afrag(Fhi, FSB, Mt, ks), al = afrag(Flo, FSB, Mt, ks);
        o2a[Mt] = MFMA16(al, bh, MFMA16(ah, bl, MFMA16(ah, bh, o2a[Mt])));
      }
    }
#pragma unroll
    for (int Mt = 0; Mt < 4; ++Mt) {
      f32x4 d = relu4(o2a[Mt]);
      omax = fmaxf(omax, fmaxf(fmaxf(d[0], d[1]), fmaxf(d[2], d[3])));
    }
    __syncthreads();   // B4: o2 F-reads done before next stage-in
  }
  omax = fmaxf(omax, __shfl_xor(omax, 16));
  omax = fmaxf(omax, __shfl_xor(omax, 32));
  if (lane < 16)
    atomicMax(&out[b * 128 + w * 16 + lane], __float_as_uint(omax));
}

extern "C" void kernel_launch(void* const* d_in, const int* in_sizes, int n_in,
                              void* d_out, int out_size, void* d_ws, size_t ws_size,
                              hipStream_t stream) {
  const float* x    = (const float*)d_in[0];
  const int*   cls  = (const int*)d_in[1];
  const float* w_in = (const float*)d_in[2];
  const float* b_in = (const float*)d_in[3];
  const float* w1   = (const float*)d_in[4];
  const float* b1   = (const float*)d_in[5];
  const float* w2   = (const float*)d_in[6];
  const float* b2   = (const float*)d_in[7];
  const float* w3   = (const float*)d_in[8];
  const float* b3   = (const float*)d_in[9];
  const float* wo1  = (const float*)d_in[10];
  const float* bo1  = (const float*)d_in[11];
  const float* wo2  = (const float*)d_in[12];
  const float* bo2  = (const float*)d_in[13];

  char* ws = (char*)d_ws;
  unsigned* f3g = (unsigned*)ws;                            // 64 MB packed hi|lo
  unsigned* part0 = (unsigned*)(ws + ((size_t)64 << 20));   // 3 x 8 KB
  unsigned* part1 = part0 + 8 * 2048;
  unsigned* part2 = part1 + 8 * 2048;
  float* poolc1 = (float*)(part2 + 8 * 2048);               // 8*1024
  float* poolc2 = poolc1 + 8 * 1024;
  float* poolco = poolc2 + 8 * 1024;                        // 8*2048
  unsigned* arena = (unsigned*)(poolco + 8 * 2048);         // 288*512 dwords

  hipMemsetAsync(d_out, 0, 1024 * sizeof(float), stream);
  hipMemsetAsync(part0, 0, 3 * 8 * 2048 * sizeof(unsigned), stream);

  prep_frags<<<N_UNITS, 64, 0, stream>>>(w_in, w1, w2, w3, wo1, wo2, arena);
  k0_kern<<<NBLK, TPB, 0, stream>>>(x, cls, b_in, b1, b2, b3, arena, f3g, part0);
  pool_reduce_kern<64><<<8, 1024, 0, stream>>>(part0, w1 + (size_t)64 * 256, b1 + 64, poolc1);
  kmid_kern<<<NBLK, TPB, 0, stream>>>(f3g, arena, poolc1, part1, cls, cls + NPTS,
                                      b2 + 128, b3 + 128, U_W1_1, U_W2_1, U_W3_1);
  pool_reduce_kern<64><<<8, 1024, 0, stream>>>(part1, w1 + (size_t)2 * 64 * 256, b1 + 128, poolc2);
  kmid_kern<<<NBLK, TPB, 0, stream>>>(f3g, arena, poolc2, part2, cls + NPTS, cls + 2 * NPTS,
                                      b2 + 256, b3 + 256, U_W1_2, U_W2_2, U_W3_2);
  pool_reduce_kern<128><<<8, 1024, 0, stream>>>(part2, wo1, bo1, poolco);
  k3_kern<<<NBLK, TPB, 0, stream>>>(f3g, arena, poolco, cls + 2 * NPTS, bo2, (unsigned*)d_out);
}